// Round 13
// baseline (2322.221 us; speedup 1.0000x reference)
//
#include <hip/hip_runtime.h>
#include <hip/hip_cooperative_groups.h>

namespace cg = cooperative_groups;

#define M_CH 2
#define J_F 2000
#define I_F 2049
#define K_B 8
#define N_IT 5
#define NMF_EPS 1e-20f
#define IP_EPS 1e-20f
#define CGRID 1024

// ---------------- init: T[n][i][k], V[n][k][j], W[i] = eye ----------------
__global__ void k_init(const float* __restrict__ T0, const float* __restrict__ V0,
                       float* __restrict__ T, float* __restrict__ V, float* __restrict__ W) {
  int t = blockIdx.x * blockDim.x + threadIdx.x;
  int stride = gridDim.x * blockDim.x;
  for (int idx = t; idx < 2 * I_F * K_B; idx += stride) {
    int n = idx / (I_F * K_B);
    int r = idx % (I_F * K_B);
    int i = r / K_B, k = r % K_B;
    T[idx] = T0[(i * K_B + k) * M_CH + n];
  }
  for (int idx = t; idx < 2 * K_B * J_F; idx += stride) {
    int n = idx / (K_B * J_F);
    int r = idx % (K_B * J_F);
    int k = r / J_F, j = r % J_F;
    V[idx] = V0[(k * J_F + j) * M_CH + n];
  }
  for (int i = t; i < I_F; i += stride) {
    W[i * 8 + 0] = 1.f; W[i * 8 + 1] = 0.f; W[i * 8 + 2] = 0.f; W[i * 8 + 3] = 0.f;
    W[i * 8 + 4] = 0.f; W[i * 8 + 5] = 0.f; W[i * 8 + 6] = 1.f; W[i * 8 + 7] = 0.f;
  }
}

// ------------- pack X j-major: Xp[j][i] = (x0r,x0i,x1r,x1i) -------------
__global__ __launch_bounds__(256) void k_pack(const float2* __restrict__ X,
                                              float4* __restrict__ Xp) {
  const int i = blockIdx.x * 256 + threadIdx.x;
  if (i >= I_F) return;
  const int j0 = blockIdx.y * 8;
  const int jend = min(8, J_F - j0);
  for (int jj = 0; jj < jend; ++jj) {
    const int j = j0 + jj;
    float2 a = X[(size_t)j * I_F + i];
    float2 b = X[(size_t)(J_F + j) * I_F + i];
    Xp[(size_t)j * I_F + i] = make_float4(a.x, a.y, b.x, b.y);
  }
}

// ------ pack X i-major via 32x32 LDS tile transpose: Xpt[i][j] ------
__global__ __launch_bounds__(256) void k_packT(const float2* __restrict__ X,
                                               float4* __restrict__ Xpt) {
  __shared__ float4 Tl[32][33];
  const int tid = threadIdx.x;
  const int i0 = blockIdx.x * 32, j0 = blockIdx.y * 32;
  const int la = tid & 31, su = tid >> 5;
#pragma unroll
  for (int p = 0; p < 4; ++p) {
    int jj = su + p * 8;
    int i = i0 + la, j = j0 + jj;
    if (i < I_F && j < J_F) {
      float2 a = X[(size_t)j * I_F + i];
      float2 b = X[(size_t)(J_F + j) * I_F + i];
      Tl[la][jj] = make_float4(a.x, a.y, b.x, b.y);
    }
  }
  __syncthreads();
#pragma unroll
  for (int p = 0; p < 4; ++p) {
    int ii = su + p * 8;
    int i = i0 + ii, j = j0 + la;
    if (i < I_F && j < J_F) Xpt[(size_t)i * J_F + j] = Tl[ii][la];
  }
}

__device__ __forceinline__ float4 load_x(const float4* Xp, const float2* X,
                                         int pk, size_t j, int i) {
  if (pk) return Xp[j * I_F + i];
  float2 a = X[j * I_F + i];
  float2 b = X[(size_t)J_F * I_F + j * I_F + i];
  return make_float4(a.x, a.y, b.x, b.y);
}

__device__ __forceinline__ float4 load_xt(const float4* Xpt, const float2* X,
                                          int pk, int i, int j) {
  if (pk) return Xpt[(size_t)i * J_F + j];
  float2 a = X[(size_t)j * I_F + i];
  float2 b = X[(size_t)(J_F + j) * I_F + i];
  return make_float4(a.x, a.y, b.x, b.y);
}

// ==== T row body: block handles row i, threads stride j, reduce, update T ====
__device__ __forceinline__ void t_row(const int i, const float4* __restrict__ Xpt,
                                      const float2* __restrict__ X, const int pkt,
                                      const float* __restrict__ W, float* __restrict__ T,
                                      const float* __restrict__ V, float (*red)[32]) {
  const int tid = threadIdx.x;
  float tr0[K_B], tr1[K_B];
#pragma unroll
  for (int k = 0; k < K_B; ++k) {
    tr0[k] = T[(size_t)i * 8 + k];
    tr1[k] = T[((size_t)I_F + i) * 8 + k];
  }
  const float4 w0 = ((const float4*)W)[i * 2];
  const float4 w1 = ((const float4*)W)[i * 2 + 1];
  float num0[K_B] = {}, den0[K_B] = {}, num1[K_B] = {}, den1[K_B] = {};
  for (int j = tid; j < J_F; j += 256) {
    float4 x = load_xt(Xpt, X, pkt, i, j);
    float yr = w0.x * x.x - w0.y * x.y + w0.z * x.z - w0.w * x.w;
    float yi = w0.x * x.y + w0.y * x.x + w0.z * x.w + w0.w * x.z;
    float p0 = yr * yr + yi * yi;
    float zr = w1.x * x.x - w1.y * x.y + w1.z * x.z - w1.w * x.w;
    float zi = w1.x * x.y + w1.y * x.x + w1.z * x.w + w1.w * x.z;
    float p1 = zr * zr + zi * zi;
    float v0[K_B], v1[K_B];
    float R0 = 0.f, R1 = 0.f;
#pragma unroll
    for (int k = 0; k < K_B; ++k) {
      v0[k] = V[(size_t)k * J_F + j];           R0 += tr0[k] * v0[k];
      v1[k] = V[(size_t)(K_B + k) * J_F + j];   R1 += tr1[k] * v1[k];
    }
    float a0 = p0 / (R0 * R0), b0 = 1.0f / R0;
    float a1 = p1 / (R1 * R1), b1 = 1.0f / R1;
#pragma unroll
    for (int k = 0; k < K_B; ++k) {
      num0[k] += a0 * v0[k]; den0[k] += b0 * v0[k];
      num1[k] += a1 * v1[k]; den1[k] += b1 * v1[k];
    }
  }
  const int lane = tid & 63, wid = tid >> 6;
#pragma unroll
  for (int k = 0; k < K_B; ++k) {
    float a0 = num0[k], b0 = den0[k], a1 = num1[k], b1 = den1[k];
#pragma unroll
    for (int off = 32; off > 0; off >>= 1) {
      a0 += __shfl_xor(a0, off, 64);
      b0 += __shfl_xor(b0, off, 64);
      a1 += __shfl_xor(a1, off, 64);
      b1 += __shfl_xor(b1, off, 64);
    }
    if (lane == 0) {
      red[wid][k] = a0; red[wid][8 + k] = b0;
      red[wid][16 + k] = a1; red[wid][24 + k] = b1;
    }
  }
  __syncthreads();
  if (tid < 32) red[0][tid] = red[0][tid] + red[1][tid] + red[2][tid] + red[3][tid];
  __syncthreads();
  if (tid < 16) {
    int n = tid >> 3, k = tid & 7;
    float nu = red[0][n * 16 + k];
    float de = red[0][n * 16 + 8 + k];
    size_t idx = ((size_t)n * I_F + i) * 8 + k;
    float told = T[idx];
    T[idx] = fmaxf(told * sqrtf(nu / de), NMF_EPS);
  }
  __syncthreads();  // protect red across loop trips
}

// ==== V row body: block handles column j, threads stride i, update V ====
__device__ __forceinline__ void v_row(const int j, const float4* __restrict__ Xp,
                                      const float2* __restrict__ X, const int pkj,
                                      const float* __restrict__ W, const float* __restrict__ T,
                                      float* __restrict__ V, float (*red)[32]) {
  const int tid = threadIdx.x;
  float vold0[K_B], vold1[K_B];
#pragma unroll
  for (int k = 0; k < K_B; ++k) {
    vold0[k] = V[(size_t)k * J_F + j];
    vold1[k] = V[(size_t)(K_B + k) * J_F + j];
  }
  float num0[K_B] = {}, den0[K_B] = {}, num1[K_B] = {}, den1[K_B] = {};
  const float* T1 = T + (size_t)I_F * K_B;
  for (int i = tid; i < I_F; i += 256) {
    float4 x = load_x(Xp, X, pkj, (size_t)j, i);
    const float4 wa = ((const float4*)W)[i * 2];
    const float4 wb = ((const float4*)W)[i * 2 + 1];
    float yr = wa.x * x.x - wa.y * x.y + wa.z * x.z - wa.w * x.w;
    float yi = wa.x * x.y + wa.y * x.x + wa.z * x.w + wa.w * x.z;
    float p0 = yr * yr + yi * yi;
    float zr = wb.x * x.x - wb.y * x.y + wb.z * x.z - wb.w * x.w;
    float zi = wb.x * x.y + wb.y * x.x + wb.z * x.w + wb.w * x.z;
    float p1 = zr * zr + zi * zi;
    const float4 ta = *(const float4*)&T[i * 8];
    const float4 tb = *(const float4*)&T[i * 8 + 4];
    const float4 tc = *(const float4*)&T1[i * 8];
    const float4 td = *(const float4*)&T1[i * 8 + 4];
    float t0[K_B] = {ta.x, ta.y, ta.z, ta.w, tb.x, tb.y, tb.z, tb.w};
    float t1[K_B] = {tc.x, tc.y, tc.z, tc.w, td.x, td.y, td.z, td.w};
    float R0 = 0.f, R1 = 0.f;
#pragma unroll
    for (int k = 0; k < K_B; ++k) { R0 += t0[k] * vold0[k]; R1 += t1[k] * vold1[k]; }
    float a0 = p0 / (R0 * R0), b0 = 1.0f / R0;
    float a1 = p1 / (R1 * R1), b1 = 1.0f / R1;
#pragma unroll
    for (int k = 0; k < K_B; ++k) {
      num0[k] += a0 * t0[k]; den0[k] += b0 * t0[k];
      num1[k] += a1 * t1[k]; den1[k] += b1 * t1[k];
    }
  }
  const int lane = tid & 63, wid = tid >> 6;
#pragma unroll
  for (int k = 0; k < K_B; ++k) {
    float a0 = num0[k], b0 = den0[k], a1 = num1[k], b1 = den1[k];
#pragma unroll
    for (int off = 32; off > 0; off >>= 1) {
      a0 += __shfl_xor(a0, off, 64);
      b0 += __shfl_xor(b0, off, 64);
      a1 += __shfl_xor(a1, off, 64);
      b1 += __shfl_xor(b1, off, 64);
    }
    if (lane == 0) {
      red[wid][k] = a0; red[wid][8 + k] = b0;
      red[wid][16 + k] = a1; red[wid][24 + k] = b1;
    }
  }
  __syncthreads();
  if (tid < 32) red[0][tid] = red[0][tid] + red[1][tid] + red[2][tid] + red[3][tid];
  __syncthreads();
  if (tid < 16) {
    int n = tid >> 3, k = tid & 7;
    float nu = red[0][n * 16 + k];
    float de = red[0][n * 16 + 8 + k];
    size_t idx = ((size_t)n * K_B + k) * J_F + j;
    float vo = V[idx];
    V[idx] = fmaxf(vo * sqrtf(nu / de), NMF_EPS);
  }
  __syncthreads();
}

// ==== D row body: block handles row i, reduce 8 sums, thread0 solves W ====
__device__ __forceinline__ void d_row(const int i, const float4* __restrict__ Xpt,
                                      const float2* __restrict__ X, const int pkt,
                                      const float* __restrict__ T, const float* __restrict__ V,
                                      float* __restrict__ W, float (*red)[32]) {
  const int tid = threadIdx.x;
  float tr0[K_B], tr1[K_B];
#pragma unroll
  for (int k = 0; k < K_B; ++k) {
    tr0[k] = T[(size_t)i * K_B + k];
    tr1[k] = T[((size_t)I_F + i) * K_B + k];
  }
  float acc[8] = {};
  for (int j = tid; j < J_F; j += 256) {
    float4 x = load_xt(Xpt, X, pkt, i, j);
    float R0 = 0.f, R1 = 0.f;
#pragma unroll
    for (int k = 0; k < K_B; ++k) {
      R0 += tr0[k] * V[(size_t)k * J_F + j];
      R1 += tr1[k] * V[(size_t)(K_B + k) * J_F + j];
    }
    float wv0 = 1.0f / (R0 + IP_EPS);
    float wv1 = 1.0f / (R1 + IP_EPS);
    float p00 = x.x * x.x + x.y * x.y;
    float p11 = x.z * x.z + x.w * x.w;
    float pr = x.x * x.z + x.y * x.w;
    float pi = x.y * x.z - x.x * x.w;
    acc[0] += wv0 * p00; acc[1] += wv0 * p11; acc[2] += wv0 * pr; acc[3] += wv0 * pi;
    acc[4] += wv1 * p00; acc[5] += wv1 * p11; acc[6] += wv1 * pr; acc[7] += wv1 * pi;
  }
  const int lane = tid & 63, wid = tid >> 6;
#pragma unroll
  for (int v = 0; v < 8; ++v) {
    float a = acc[v];
#pragma unroll
    for (int off = 32; off > 0; off >>= 1) a += __shfl_xor(a, off, 64);
    if (lane == 0) red[wid][v] = a;
  }
  __syncthreads();
  if (tid < 8) red[0][tid] = red[0][tid] + red[1][tid] + red[2][tid] + red[3][tid];
  __syncthreads();
  if (tid == 0) {
    float4 wa = ((const float4*)W)[i * 2];
    float4 wb = ((const float4*)W)[i * 2 + 1];
    float w00r = wa.x, w00i = wa.y, w01r = wa.z, w01i = wa.w;
    float w10r = wb.x, w10i = wb.y, w11r = wb.z, w11i = wb.w;
    const float invJ = 1.0f / (float)J_F;
#pragma unroll
    for (int n = 0; n < 2; ++n) {
      float d00 = red[0][n * 4 + 0] * invJ + IP_EPS;
      float d11 = red[0][n * 4 + 1] * invJ + IP_EPS;
      float d01r = red[0][n * 4 + 2] * invJ;
      float d01i = red[0][n * 4 + 3] * invJ;
      float A00r = w00r * d00 + (w01r * d01r + w01i * d01i);
      float A00i = w00i * d00 + (w01i * d01r - w01r * d01i);
      float A01r = (w00r * d01r - w00i * d01i) + w01r * d11;
      float A01i = (w00r * d01i + w00i * d01r) + w01i * d11;
      float A10r = w10r * d00 + (w11r * d01r + w11i * d01i);
      float A10i = w10i * d00 + (w11i * d01r - w11r * d01i);
      float A11r = (w10r * d01r - w10i * d01i) + w11r * d11;
      float A11i = (w10r * d01i + w10i * d01r) + w11i * d11;
      float detr = (A00r * A11r - A00i * A11i) - (A01r * A10r - A01i * A10i);
      float deti = (A00r * A11i + A00i * A11r) - (A01r * A10i + A01i * A10r);
      float idet = 1.0f / (detr * detr + deti * deti);
      float n0r, n0i, n1r, n1i;
      if (n == 0) { n0r = A11r; n0i = A11i; n1r = -A10r; n1i = -A10i; }
      else        { n0r = -A01r; n0i = -A01i; n1r = A00r; n1i = A00i; }
      float b0r = (n0r * detr + n0i * deti) * idet;
      float b0i = (n0i * detr - n0r * deti) * idet;
      float b1r = (n1r * detr + n1i * deti) * idet;
      float b1i = (n1i * detr - n1r * deti) * idet;
      float cr = d01r * b1r - d01i * b1i;
      float ci = d01r * b1i + d01i * b1r;
      float quad = d00 * (b0r * b0r + b0i * b0i) + d11 * (b1r * b1r + b1i * b1i)
                 + 2.0f * (b0r * cr + b0i * ci);
      float s = 1.0f / sqrtf(quad + IP_EPS);
      if (n == 0) { w00r = b0r * s; w00i = -b0i * s; w01r = b1r * s; w01i = -b1i * s; }
      else        { w10r = b0r * s; w10i = -b0i * s; w11r = b1r * s; w11i = -b1i * s; }
    }
    ((float4*)W)[i * 2]     = make_float4(w00r, w00i, w01r, w01i);
    ((float4*)W)[i * 2 + 1] = make_float4(w10r, w10i, w11r, w11i);
  }
  __syncthreads();
}

// ==== final tile body ====
__device__ __forceinline__ void final_tile(const int b, const float4* __restrict__ Xp,
                                           const float2* __restrict__ X, const int pkj,
                                           const float* __restrict__ W,
                                           float2* __restrict__ out) {
  const int bx = b % 9, by = b / 9;
  const int i = bx * 256 + threadIdx.x;
  if (i >= I_F) return;
  const float4 wa = ((const float4*)W)[i * 2];
  const float4 wb = ((const float4*)W)[i * 2 + 1];
  const int j0 = by * 8;
  const int jend = min(8, J_F - j0);
  for (int jj = 0; jj < jend; ++jj) {
    const int j = j0 + jj;
    float4 x = load_x(Xp, X, pkj, (size_t)j, i);
    float y0r = wa.x * x.x - wa.y * x.y + wa.z * x.z - wa.w * x.w;
    float y0i = wa.x * x.y + wa.y * x.x + wa.z * x.w + wa.w * x.z;
    out[(size_t)j * I_F + i] = make_float2(y0r, y0i);
    float y1r = wb.x * x.x - wb.y * x.y + wb.z * x.z - wb.w * x.w;
    float y1i = wb.x * x.y + wb.y * x.x + wb.z * x.w + wb.w * x.z;
    out[(size_t)(J_F + j) * I_F + i] = make_float2(y1r, y1i);
  }
}

// ==================== cooperative mega-kernel ====================
template<int PKT, int PKJ>
__global__ __launch_bounds__(256, 4) void k_coop(const float4* __restrict__ Xpt,
                                                 const float4* __restrict__ Xp,
                                                 const float2* __restrict__ X,
                                                 float* __restrict__ W,
                                                 float* __restrict__ T,
                                                 float* __restrict__ V,
                                                 float2* __restrict__ out) {
  cg::grid_group grid = cg::this_grid();
  __shared__ float red[4][32];
  const int nb = gridDim.x;
  for (int it = 0; it < N_IT; ++it) {
    for (int i = blockIdx.x; i < I_F; i += nb) t_row(i, Xpt, X, PKT, W, T, V, red);
    grid.sync();
    for (int j = blockIdx.x; j < J_F; j += nb) v_row(j, Xp, X, PKJ, W, T, V, red);
    grid.sync();
    for (int i = blockIdx.x; i < I_F; i += nb) d_row(i, Xpt, X, PKT, T, V, W, red);
    grid.sync();
  }
  for (int b = blockIdx.x; b < 9 * 250; b += nb) final_tile(b, Xp, X, PKJ, W, out);
}

// ---- standalone fallback kernels (same bodies) ----
template<int PK>
__global__ __launch_bounds__(256) void k_T_rows(const float4* __restrict__ Xpt,
                                                const float2* __restrict__ X,
                                                const float* __restrict__ W,
                                                float* __restrict__ T,
                                                const float* __restrict__ V) {
  __shared__ float red[4][32];
  t_row(blockIdx.x, Xpt, X, PK, W, T, V, red);
}

template<int PK>
__global__ __launch_bounds__(256) void k_v_update(const float4* __restrict__ Xp,
                                                  const float2* __restrict__ X,
                                                  const float* __restrict__ W,
                                                  const float* __restrict__ T,
                                                  float* __restrict__ V) {
  __shared__ float red[4][32];
  v_row(blockIdx.x, Xp, X, PK, W, T, V, red);
}

template<int PK>
__global__ __launch_bounds__(256) void k_d_rows(const float4* __restrict__ Xpt,
                                                const float2* __restrict__ X,
                                                const float* __restrict__ T,
                                                const float* __restrict__ V,
                                                float* __restrict__ W) {
  __shared__ float red[4][32];
  d_row(blockIdx.x, Xpt, X, PK, T, V, W, red);
}

template<int PK>
__global__ __launch_bounds__(256) void k_final(const float4* __restrict__ Xp,
                                               const float2* __restrict__ X,
                                               const float* __restrict__ W,
                                               float2* __restrict__ out) {
  final_tile(blockIdx.x + blockIdx.y * 9, Xp, X, PK, W, out);
}

extern "C" void kernel_launch(void* const* d_in, const int* in_sizes, int n_in,
                              void* d_out, int out_size, void* d_ws, size_t ws_size,
                              hipStream_t stream) {
  const float2* X = (const float2*)d_in[0];
  const float* T0 = (const float*)d_in[1];
  const float* V0 = (const float*)d_in[2];
  float2* outp = (float2*)d_out;
  char* ws = (char*)d_ws;
  size_t off = 0;
  auto alloc = [&](size_t bytes) -> void* {
    void* p = ws + off;
    off = (off + bytes + 255) & ~(size_t)255;
    return p;
  };
  float* W = (float*)alloc((size_t)I_F * 8 * 4);
  float* T = (float*)alloc((size_t)2 * I_F * K_B * 4);
  float* V = (float*)alloc((size_t)2 * K_B * J_F * 4);
  const size_t x_sz = (size_t)J_F * I_F * 16;  // 65.6 MB each
  float4* Xpt = nullptr;
  float4* Xp = nullptr;
  if (off + x_sz <= ws_size) Xpt = (float4*)alloc(x_sz);
  if (Xpt && off + x_sz <= ws_size) Xp = (float4*)alloc(x_sz);
  const int pkt = Xpt != nullptr, pkj = Xp != nullptr;

  k_init<<<128, 256, 0, stream>>>(T0, V0, T, V, W);
  if (pkt) k_packT<<<dim3(65, 63), 256, 0, stream>>>(X, Xpt);
  if (pkj) k_pack<<<dim3(9, 250), 256, 0, stream>>>(X, Xp);

  // ---- try single cooperative kernel for all iterations + final ----
  void* args[] = {(void*)&Xpt, (void*)&Xp, (void*)&X,
                  (void*)&W, (void*)&T, (void*)&V, (void*)&outp};
  const void* fn;
  if (pkt && pkj) fn = (const void*)&k_coop<1, 1>;
  else if (pkt)   fn = (const void*)&k_coop<1, 0>;
  else            fn = (const void*)&k_coop<0, 0>;
  hipError_t e = hipLaunchCooperativeKernel(fn, dim3(CGRID), dim3(256), args, 0, stream);
  if (e == hipSuccess) return;
  (void)hipGetLastError();

  // ---- fallback: R12 multi-launch path ----
  if (pkt && pkj) {
    for (int it = 0; it < N_IT; ++it) {
      k_T_rows<1><<<I_F, 256, 0, stream>>>(Xpt, X, W, T, V);
      k_v_update<1><<<J_F, 256, 0, stream>>>(Xp, X, W, T, V);
      k_d_rows<1><<<I_F, 256, 0, stream>>>(Xpt, X, T, V, W);
    }
    k_final<1><<<dim3(9, 250), 256, 0, stream>>>(Xp, X, W, outp);
  } else if (pkt) {
    for (int it = 0; it < N_IT; ++it) {
      k_T_rows<1><<<I_F, 256, 0, stream>>>(Xpt, X, W, T, V);
      k_v_update<0><<<J_F, 256, 0, stream>>>(nullptr, X, W, T, V);
      k_d_rows<1><<<I_F, 256, 0, stream>>>(Xpt, X, T, V, W);
    }
    k_final<0><<<dim3(9, 250), 256, 0, stream>>>(nullptr, X, W, outp);
  } else {
    for (int it = 0; it < N_IT; ++it) {
      k_T_rows<0><<<I_F, 256, 0, stream>>>(nullptr, X, W, T, V);
      k_v_update<0><<<J_F, 256, 0, stream>>>(nullptr, X, W, T, V);
      k_d_rows<0><<<I_F, 256, 0, stream>>>(nullptr, X, T, V, W);
    }
    k_final<0><<<dim3(9, 250), 256, 0, stream>>>(nullptr, X, W, outp);
  }
}

// Round 14
// 586.203 us; speedup vs baseline: 3.9615x; 3.9615x over previous
//
#include <hip/hip_runtime.h>

#define M_CH 2
#define J_F 2000
#define I_F 2049
#define K_B 8
#define N_IT 5
#define NMF_EPS 1e-20f
#define IP_EPS 1e-20f

#define NB_PACKT (65 * 63)
#define NB_PACK (9 * 250)
#define NB_INIT 128

__device__ __forceinline__ float4 load_x(const float4* Xp, const float2* X,
                                         int pk, size_t j, int i) {
  if (pk) return Xp[j * I_F + i];
  float2 a = X[j * I_F + i];
  float2 b = X[(size_t)J_F * I_F + j * I_F + i];
  return make_float4(a.x, a.y, b.x, b.y);
}

__device__ __forceinline__ float4 load_xt(const float4* Xpt, const float2* X,
                                          int pk, int i, int j) {
  if (pk) return Xpt[(size_t)i * J_F + j];
  float2 a = X[(size_t)j * I_F + i];
  float2 b = X[(size_t)(J_F + j) * I_F + i];
  return make_float4(a.x, a.y, b.x, b.y);
}

// ===== fused setup: packT | pack | init (independent work, one launch) =====
template<int PKT, int PKJ>
__global__ __launch_bounds__(256) void k_setup(const float2* __restrict__ X,
                                               const float* __restrict__ T0,
                                               const float* __restrict__ V0,
                                               float* __restrict__ Tt,
                                               float* __restrict__ Vt,
                                               float* __restrict__ W,
                                               float4* __restrict__ Xpt,
                                               float4* __restrict__ Xp) {
  int b = blockIdx.x;
  const int tid = threadIdx.x;
  if (b < NB_PACKT) {
    if (!PKT) return;
    __shared__ float4 Tl[32][33];
    const int i0 = (b % 65) * 32, j0 = (b / 65) * 32;
    const int la = tid & 31, su = tid >> 5;
#pragma unroll
    for (int p = 0; p < 4; ++p) {
      int jj = su + p * 8;
      int i = i0 + la, j = j0 + jj;
      if (i < I_F && j < J_F) {
        float2 a = X[(size_t)j * I_F + i];
        float2 c = X[(size_t)(J_F + j) * I_F + i];
        Tl[la][jj] = make_float4(a.x, a.y, c.x, c.y);
      }
    }
    __syncthreads();
#pragma unroll
    for (int p = 0; p < 4; ++p) {
      int ii = su + p * 8;
      int i = i0 + ii, j = j0 + la;
      if (i < I_F && j < J_F) Xpt[(size_t)i * J_F + j] = Tl[ii][la];
    }
    return;
  }
  b -= NB_PACKT;
  if (b < NB_PACK) {
    if (!PKJ) return;
    const int i = (b % 9) * 256 + tid;
    if (i >= I_F) return;
    const int j0 = (b / 9) * 8;
    const int jend = min(8, J_F - j0);
    for (int jj = 0; jj < jend; ++jj) {
      const int j = j0 + jj;
      float2 a = X[(size_t)j * I_F + i];
      float2 c = X[(size_t)(J_F + j) * I_F + i];
      Xp[(size_t)j * I_F + i] = make_float4(a.x, a.y, c.x, c.y);
    }
    return;
  }
  b -= NB_PACK;
  int t = b * 256 + tid;
  const int stride = NB_INIT * 256;
  for (int idx = t; idx < I_F * 16; idx += stride) {
    int i = idx >> 4, c = idx & 15;
    int n = c >> 3, k = c & 7;
    Tt[idx] = T0[(i * K_B + k) * M_CH + n];
  }
  for (int idx = t; idx < J_F * 16; idx += stride) {
    int j = idx >> 4, c = idx & 15;
    int n = c >> 3, k = c & 7;
    Vt[idx] = V0[(k * J_F + j) * M_CH + n];
  }
  for (int i = t; i < I_F; i += stride) {
    W[i * 8 + 0] = 1.f; W[i * 8 + 1] = 0.f; W[i * 8 + 2] = 0.f; W[i * 8 + 3] = 0.f;
    W[i * 8 + 4] = 0.f; W[i * 8 + 5] = 0.f; W[i * 8 + 6] = 1.f; W[i * 8 + 7] = 0.f;
  }
}

// ==== T body: row i, threads stride j, reduce, update Tt[i][16] ====
__device__ __forceinline__ void t_body(const int i, const float4* __restrict__ Xpt,
                                       const float2* __restrict__ X, const int pkt,
                                       const float4 w0, const float4 w1,
                                       float* __restrict__ Tt, const float* __restrict__ Vt,
                                       float (*red)[32]) {
  const int tid = threadIdx.x;
  const float4* tt = (const float4*)(Tt + (size_t)i * 16);
  const float4 ta = tt[0], tb = tt[1], tc = tt[2], td = tt[3];
  const float tr0[K_B] = {ta.x, ta.y, ta.z, ta.w, tb.x, tb.y, tb.z, tb.w};
  const float tr1[K_B] = {tc.x, tc.y, tc.z, tc.w, td.x, td.y, td.z, td.w};
  float num0[K_B] = {}, den0[K_B] = {}, num1[K_B] = {}, den1[K_B] = {};
  for (int j = tid; j < J_F; j += 256) {
    float4 x = load_xt(Xpt, X, pkt, i, j);
    float yr = w0.x * x.x - w0.y * x.y + w0.z * x.z - w0.w * x.w;
    float yi = w0.x * x.y + w0.y * x.x + w0.z * x.w + w0.w * x.z;
    float p0 = yr * yr + yi * yi;
    float zr = w1.x * x.x - w1.y * x.y + w1.z * x.z - w1.w * x.w;
    float zi = w1.x * x.y + w1.y * x.x + w1.z * x.w + w1.w * x.z;
    float p1 = zr * zr + zi * zi;
    const float4* vv = (const float4*)(Vt + (size_t)j * 16);
    const float4 va = vv[0], vb = vv[1], vc = vv[2], vd = vv[3];
    const float v0[K_B] = {va.x, va.y, va.z, va.w, vb.x, vb.y, vb.z, vb.w};
    const float v1[K_B] = {vc.x, vc.y, vc.z, vc.w, vd.x, vd.y, vd.z, vd.w};
    float R0 = 0.f, R1 = 0.f;
#pragma unroll
    for (int k = 0; k < K_B; ++k) { R0 += tr0[k] * v0[k]; R1 += tr1[k] * v1[k]; }
    float a0 = p0 / (R0 * R0), b0 = 1.0f / R0;
    float a1 = p1 / (R1 * R1), b1 = 1.0f / R1;
#pragma unroll
    for (int k = 0; k < K_B; ++k) {
      num0[k] += a0 * v0[k]; den0[k] += b0 * v0[k];
      num1[k] += a1 * v1[k]; den1[k] += b1 * v1[k];
    }
  }
  const int lane = tid & 63, wid = tid >> 6;
#pragma unroll
  for (int k = 0; k < K_B; ++k) {
    float a0 = num0[k], b0 = den0[k], a1 = num1[k], b1 = den1[k];
#pragma unroll
    for (int off = 32; off > 0; off >>= 1) {
      a0 += __shfl_xor(a0, off, 64);
      b0 += __shfl_xor(b0, off, 64);
      a1 += __shfl_xor(a1, off, 64);
      b1 += __shfl_xor(b1, off, 64);
    }
    if (lane == 0) {
      red[wid][k] = a0; red[wid][8 + k] = b0;
      red[wid][16 + k] = a1; red[wid][24 + k] = b1;
    }
  }
  __syncthreads();
  if (tid < 32) red[0][tid] = red[0][tid] + red[1][tid] + red[2][tid] + red[3][tid];
  __syncthreads();
  if (tid < 16) {
    int n = tid >> 3, k = tid & 7;
    float nu = red[0][n * 16 + k];
    float de = red[0][n * 16 + 8 + k];
    float told = Tt[(size_t)i * 16 + tid];
    Tt[(size_t)i * 16 + tid] = fmaxf(told * sqrtf(nu / de), NMF_EPS);
  }
  __syncthreads();
}

// ==== V body: column j, threads stride i, reduce, update Vt[j][16] ====
__device__ __forceinline__ void v_body(const int j, const float4* __restrict__ Xp,
                                       const float2* __restrict__ X, const int pkj,
                                       const float* __restrict__ W,
                                       const float* __restrict__ Tt,
                                       float* __restrict__ Vt, float (*red)[32]) {
  const int tid = threadIdx.x;
  const float4* vv = (const float4*)(Vt + (size_t)j * 16);
  const float4 va = vv[0], vb = vv[1], vc = vv[2], vd = vv[3];
  const float vold0[K_B] = {va.x, va.y, va.z, va.w, vb.x, vb.y, vb.z, vb.w};
  const float vold1[K_B] = {vc.x, vc.y, vc.z, vc.w, vd.x, vd.y, vd.z, vd.w};
  float num0[K_B] = {}, den0[K_B] = {}, num1[K_B] = {}, den1[K_B] = {};
  for (int i = tid; i < I_F; i += 256) {
    float4 x = load_x(Xp, X, pkj, (size_t)j, i);
    const float4 wa = ((const float4*)W)[i * 2];
    const float4 wb = ((const float4*)W)[i * 2 + 1];
    float yr = wa.x * x.x - wa.y * x.y + wa.z * x.z - wa.w * x.w;
    float yi = wa.x * x.y + wa.y * x.x + wa.z * x.w + wa.w * x.z;
    float p0 = yr * yr + yi * yi;
    float zr = wb.x * x.x - wb.y * x.y + wb.z * x.z - wb.w * x.w;
    float zi = wb.x * x.y + wb.y * x.x + wb.z * x.w + wb.w * x.z;
    float p1 = zr * zr + zi * zi;
    const float4* tt = (const float4*)(Tt + (size_t)i * 16);
    const float4 ta = tt[0], tb = tt[1], tc = tt[2], td = tt[3];
    const float t0[K_B] = {ta.x, ta.y, ta.z, ta.w, tb.x, tb.y, tb.z, tb.w};
    const float t1[K_B] = {tc.x, tc.y, tc.z, tc.w, td.x, td.y, td.z, td.w};
    float R0 = 0.f, R1 = 0.f;
#pragma unroll
    for (int k = 0; k < K_B; ++k) { R0 += t0[k] * vold0[k]; R1 += t1[k] * vold1[k]; }
    float a0 = p0 / (R0 * R0), b0 = 1.0f / R0;
    float a1 = p1 / (R1 * R1), b1 = 1.0f / R1;
#pragma unroll
    for (int k = 0; k < K_B; ++k) {
      num0[k] += a0 * t0[k]; den0[k] += b0 * t0[k];
      num1[k] += a1 * t1[k]; den1[k] += b1 * t1[k];
    }
  }
  const int lane = tid & 63, wid = tid >> 6;
#pragma unroll
  for (int k = 0; k < K_B; ++k) {
    float a0 = num0[k], b0 = den0[k], a1 = num1[k], b1 = den1[k];
#pragma unroll
    for (int off = 32; off > 0; off >>= 1) {
      a0 += __shfl_xor(a0, off, 64);
      b0 += __shfl_xor(b0, off, 64);
      a1 += __shfl_xor(a1, off, 64);
      b1 += __shfl_xor(b1, off, 64);
    }
    if (lane == 0) {
      red[wid][k] = a0; red[wid][8 + k] = b0;
      red[wid][16 + k] = a1; red[wid][24 + k] = b1;
    }
  }
  __syncthreads();
  if (tid < 32) red[0][tid] = red[0][tid] + red[1][tid] + red[2][tid] + red[3][tid];
  __syncthreads();
  if (tid < 16) {
    int n = tid >> 3, k = tid & 7;
    float nu = red[0][n * 16 + k];
    float de = red[0][n * 16 + 8 + k];
    float vo = Vt[(size_t)j * 16 + tid];
    Vt[(size_t)j * 16 + tid] = fmaxf(vo * sqrtf(nu / de), NMF_EPS);
  }
  __syncthreads();
}

// ==== D body: row i, reduce 8 sums, thread0 solves, broadcasts new W row ====
__device__ __forceinline__ void d_body(const int i, const float4* __restrict__ Xpt,
                                       const float2* __restrict__ X, const int pkt,
                                       const float* __restrict__ Tt,
                                       const float* __restrict__ Vt,
                                       float* __restrict__ W, float (*red)[32],
                                       float* wrow) {
  const int tid = threadIdx.x;
  const float4* tt = (const float4*)(Tt + (size_t)i * 16);
  const float4 ta = tt[0], tb = tt[1], tc = tt[2], td = tt[3];
  const float tr0[K_B] = {ta.x, ta.y, ta.z, ta.w, tb.x, tb.y, tb.z, tb.w};
  const float tr1[K_B] = {tc.x, tc.y, tc.z, tc.w, td.x, td.y, td.z, td.w};
  float acc[8] = {};
  for (int j = tid; j < J_F; j += 256) {
    float4 x = load_xt(Xpt, X, pkt, i, j);
    const float4* vv = (const float4*)(Vt + (size_t)j * 16);
    const float4 va = vv[0], vb = vv[1], vc = vv[2], vd = vv[3];
    const float v0[K_B] = {va.x, va.y, va.z, va.w, vb.x, vb.y, vb.z, vb.w};
    const float v1[K_B] = {vc.x, vc.y, vc.z, vc.w, vd.x, vd.y, vd.z, vd.w};
    float R0 = 0.f, R1 = 0.f;
#pragma unroll
    for (int k = 0; k < K_B; ++k) { R0 += tr0[k] * v0[k]; R1 += tr1[k] * v1[k]; }
    float wv0 = 1.0f / (R0 + IP_EPS);
    float wv1 = 1.0f / (R1 + IP_EPS);
    float p00 = x.x * x.x + x.y * x.y;
    float p11 = x.z * x.z + x.w * x.w;
    float pr = x.x * x.z + x.y * x.w;
    float pi = x.y * x.z - x.x * x.w;
    acc[0] += wv0 * p00; acc[1] += wv0 * p11; acc[2] += wv0 * pr; acc[3] += wv0 * pi;
    acc[4] += wv1 * p00; acc[5] += wv1 * p11; acc[6] += wv1 * pr; acc[7] += wv1 * pi;
  }
  const int lane = tid & 63, wid = tid >> 6;
#pragma unroll
  for (int v = 0; v < 8; ++v) {
    float a = acc[v];
#pragma unroll
    for (int off = 32; off > 0; off >>= 1) a += __shfl_xor(a, off, 64);
    if (lane == 0) red[wid][v] = a;
  }
  __syncthreads();
  if (tid < 8) red[0][tid] = red[0][tid] + red[1][tid] + red[2][tid] + red[3][tid];
  __syncthreads();
  if (tid == 0) {
    float4 wa = ((const float4*)W)[i * 2];
    float4 wb = ((const float4*)W)[i * 2 + 1];
    float w00r = wa.x, w00i = wa.y, w01r = wa.z, w01i = wa.w;
    float w10r = wb.x, w10i = wb.y, w11r = wb.z, w11i = wb.w;
    const float invJ = 1.0f / (float)J_F;
#pragma unroll
    for (int n = 0; n < 2; ++n) {
      float d00 = red[0][n * 4 + 0] * invJ + IP_EPS;
      float d11 = red[0][n * 4 + 1] * invJ + IP_EPS;
      float d01r = red[0][n * 4 + 2] * invJ;
      float d01i = red[0][n * 4 + 3] * invJ;
      float A00r = w00r * d00 + (w01r * d01r + w01i * d01i);
      float A00i = w00i * d00 + (w01i * d01r - w01r * d01i);
      float A01r = (w00r * d01r - w00i * d01i) + w01r * d11;
      float A01i = (w00r * d01i + w00i * d01r) + w01i * d11;
      float A10r = w10r * d00 + (w11r * d01r + w11i * d01i);
      float A10i = w10i * d00 + (w11i * d01r - w11r * d01i);
      float A11r = (w10r * d01r - w10i * d01i) + w11r * d11;
      float A11i = (w10r * d01i + w10i * d01r) + w11i * d11;
      float detr = (A00r * A11r - A00i * A11i) - (A01r * A10r - A01i * A10i);
      float deti = (A00r * A11i + A00i * A11r) - (A01r * A10i + A01i * A10r);
      float idet = 1.0f / (detr * detr + deti * deti);
      float n0r, n0i, n1r, n1i;
      if (n == 0) { n0r = A11r; n0i = A11i; n1r = -A10r; n1i = -A10i; }
      else        { n0r = -A01r; n0i = -A01i; n1r = A00r; n1i = A00i; }
      float b0r = (n0r * detr + n0i * deti) * idet;
      float b0i = (n0i * detr - n0r * deti) * idet;
      float b1r = (n1r * detr + n1i * deti) * idet;
      float b1i = (n1i * detr - n1r * deti) * idet;
      float cr = d01r * b1r - d01i * b1i;
      float ci = d01r * b1i + d01i * b1r;
      float quad = d00 * (b0r * b0r + b0i * b0i) + d11 * (b1r * b1r + b1i * b1i)
                 + 2.0f * (b0r * cr + b0i * ci);
      float s = 1.0f / sqrtf(quad + IP_EPS);
      if (n == 0) { w00r = b0r * s; w00i = -b0i * s; w01r = b1r * s; w01i = -b1i * s; }
      else        { w10r = b0r * s; w10i = -b0i * s; w11r = b1r * s; w11i = -b1i * s; }
    }
    ((float4*)W)[i * 2]     = make_float4(w00r, w00i, w01r, w01i);
    ((float4*)W)[i * 2 + 1] = make_float4(w10r, w10i, w11r, w11i);
    wrow[0] = w00r; wrow[1] = w00i; wrow[2] = w01r; wrow[3] = w01i;
    wrow[4] = w10r; wrow[5] = w10i; wrow[6] = w11r; wrow[7] = w11i;
  }
  __syncthreads();
}

// ---- standalone kernels ----
template<int PK>
__global__ __launch_bounds__(256) void k_T(const float4* __restrict__ Xpt,
                                           const float2* __restrict__ X,
                                           const float* __restrict__ W,
                                           float* __restrict__ Tt,
                                           const float* __restrict__ Vt) {
  __shared__ float red[4][32];
  const int i = blockIdx.x;
  const float4 w0 = ((const float4*)W)[i * 2];
  const float4 w1 = ((const float4*)W)[i * 2 + 1];
  t_body(i, Xpt, X, PK, w0, w1, Tt, Vt, red);
}

template<int PK>
__global__ __launch_bounds__(256) void k_V(const float4* __restrict__ Xp,
                                           const float2* __restrict__ X,
                                           const float* __restrict__ W,
                                           const float* __restrict__ Tt,
                                           float* __restrict__ Vt) {
  __shared__ float red[4][32];
  v_body(blockIdx.x, Xp, X, PK, W, Tt, Vt, red);
}

// D of iteration it fused with T of iteration it+1 (same row i, W[i] via LDS)
template<int PK, int LAST>
__global__ __launch_bounds__(256) void k_DT(const float4* __restrict__ Xpt,
                                            const float2* __restrict__ X,
                                            float* __restrict__ Tt,
                                            const float* __restrict__ Vt,
                                            float* __restrict__ W) {
  __shared__ float red[4][32];
  __shared__ float wrow[8];
  const int i = blockIdx.x;
  d_body(i, Xpt, X, PK, Tt, Vt, W, red, wrow);
  if (!LAST) {
    const float4 w0 = make_float4(wrow[0], wrow[1], wrow[2], wrow[3]);
    const float4 w1 = make_float4(wrow[4], wrow[5], wrow[6], wrow[7]);
    t_body(i, Xpt, X, PK, w0, w1, Tt, Vt, red);
  }
}

template<int PK>
__global__ __launch_bounds__(256) void k_final(const float4* __restrict__ Xp,
                                               const float2* __restrict__ X,
                                               const float* __restrict__ W,
                                               float2* __restrict__ out) {
  const int i = blockIdx.x * 256 + threadIdx.x;
  if (i >= I_F) return;
  const float4 wa = ((const float4*)W)[i * 2];
  const float4 wb = ((const float4*)W)[i * 2 + 1];
  const int j0 = blockIdx.y * 8;
  const int jend = min(8, J_F - j0);
  for (int jj = 0; jj < jend; ++jj) {
    const int j = j0 + jj;
    float4 x = load_x(Xp, X, PK, (size_t)j, i);
    float y0r = wa.x * x.x - wa.y * x.y + wa.z * x.z - wa.w * x.w;
    float y0i = wa.x * x.y + wa.y * x.x + wa.z * x.w + wa.w * x.z;
    out[(size_t)j * I_F + i] = make_float2(y0r, y0i);
    float y1r = wb.x * x.x - wb.y * x.y + wb.z * x.z - wb.w * x.w;
    float y1i = wb.x * x.y + wb.y * x.x + wb.z * x.w + wb.w * x.z;
    out[(size_t)(J_F + j) * I_F + i] = make_float2(y1r, y1i);
  }
}

extern "C" void kernel_launch(void* const* d_in, const int* in_sizes, int n_in,
                              void* d_out, int out_size, void* d_ws, size_t ws_size,
                              hipStream_t stream) {
  const float2* X = (const float2*)d_in[0];
  const float* T0 = (const float*)d_in[1];
  const float* V0 = (const float*)d_in[2];
  float2* outp = (float2*)d_out;
  char* ws = (char*)d_ws;
  size_t off = 0;
  auto alloc = [&](size_t bytes) -> void* {
    void* p = ws + off;
    off = (off + bytes + 255) & ~(size_t)255;
    return p;
  };
  float* W = (float*)alloc((size_t)I_F * 8 * 4);
  float* Tt = (float*)alloc((size_t)I_F * 16 * 4);
  float* Vt = (float*)alloc((size_t)J_F * 16 * 4);
  const size_t x_sz = (size_t)J_F * I_F * 16;
  float4* Xpt = nullptr;
  float4* Xp = nullptr;
  if (off + x_sz <= ws_size) Xpt = (float4*)alloc(x_sz);
  if (Xpt && off + x_sz <= ws_size) Xp = (float4*)alloc(x_sz);
  const int NB_SETUP = NB_PACKT + NB_PACK + NB_INIT;

  if (Xpt && Xp) {
    k_setup<1, 1><<<NB_SETUP, 256, 0, stream>>>(X, T0, V0, Tt, Vt, W, Xpt, Xp);
    k_T<1><<<I_F, 256, 0, stream>>>(Xpt, X, W, Tt, Vt);
    for (int it = 0; it < N_IT; ++it) {
      k_V<1><<<J_F, 256, 0, stream>>>(Xp, X, W, Tt, Vt);
      if (it < N_IT - 1)
        k_DT<1, 0><<<I_F, 256, 0, stream>>>(Xpt, X, Tt, Vt, W);
      else
        k_DT<1, 1><<<I_F, 256, 0, stream>>>(Xpt, X, Tt, Vt, W);
    }
    k_final<1><<<dim3(9, 250), 256, 0, stream>>>(Xp, X, W, outp);
  } else if (Xpt) {
    k_setup<1, 0><<<NB_SETUP, 256, 0, stream>>>(X, T0, V0, Tt, Vt, W, Xpt, nullptr);
    k_T<1><<<I_F, 256, 0, stream>>>(Xpt, X, W, Tt, Vt);
    for (int it = 0; it < N_IT; ++it) {
      k_V<0><<<J_F, 256, 0, stream>>>(nullptr, X, W, Tt, Vt);
      if (it < N_IT - 1)
        k_DT<1, 0><<<I_F, 256, 0, stream>>>(Xpt, X, Tt, Vt, W);
      else
        k_DT<1, 1><<<I_F, 256, 0, stream>>>(Xpt, X, Tt, Vt, W);
    }
    k_final<0><<<dim3(9, 250), 256, 0, stream>>>(nullptr, X, W, outp);
  } else {
    k_setup<0, 0><<<NB_SETUP, 256, 0, stream>>>(X, T0, V0, Tt, Vt, W, nullptr, nullptr);
    k_T<0><<<I_F, 256, 0, stream>>>(nullptr, X, W, Tt, Vt);
    for (int it = 0; it < N_IT; ++it) {
      k_V<0><<<J_F, 256, 0, stream>>>(nullptr, X, W, Tt, Vt);
      if (it < N_IT - 1)
        k_DT<0, 0><<<I_F, 256, 0, stream>>>(nullptr, X, Tt, Vt, W);
      else
        k_DT<0, 1><<<I_F, 256, 0, stream>>>(nullptr, X, Tt, Vt, W);
    }
    k_final<0><<<dim3(9, 250), 256, 0, stream>>>(nullptr, X, W, outp);
  }
}

// Round 15
// 467.872 us; speedup vs baseline: 4.9634x; 1.2529x over previous
//
#include <hip/hip_runtime.h>
#include <hip/hip_fp16.h>

#define M_CH 2
#define J_F 2000
#define I_F 2049
#define K_B 8
#define N_IT 5
#define NMF_EPS 1e-20f
#define IP_EPS 1e-20f

#define NB_PACKT (65 * 63)
#define NB_PACK (9 * 250)
#define NB_INIT 128

__device__ __forceinline__ float2 h2f(unsigned u) {
  __half2 h = *reinterpret_cast<__half2*>(&u);
  return __half22float2(h);
}
__device__ __forceinline__ float4 h4f(unsigned lo, unsigned hi) {
  float2 a = h2f(lo), b = h2f(hi);
  return make_float4(a.x, a.y, b.x, b.y);
}
__device__ __forceinline__ unsigned f2h(float a, float b) {
  __half2 h = __floats2half2_rn(a, b);
  return *reinterpret_cast<unsigned*>(&h);
}

// ===== fused setup: packT(fp16) | pack(fp16) | init =====
template<int PK>
__global__ __launch_bounds__(256) void k_setup(const float2* __restrict__ X,
                                               const float* __restrict__ T0,
                                               const float* __restrict__ V0,
                                               float* __restrict__ T,
                                               float* __restrict__ V,
                                               float* __restrict__ W,
                                               __half* __restrict__ Xht,
                                               __half* __restrict__ Xhj) {
  int b = blockIdx.x;
  const int tid = threadIdx.x;
  if (b < NB_PACKT) {
    if (!PK) return;
    __shared__ float4 Tl[32][33];
    const int i0 = (b % 65) * 32, j0 = (b / 65) * 32;
    const int la = tid & 31, su = tid >> 5;
#pragma unroll
    for (int p = 0; p < 4; ++p) {
      int jj = su + p * 8;
      int i = i0 + la, j = j0 + jj;
      if (i < I_F && j < J_F) {
        float2 a = X[(size_t)j * I_F + i];
        float2 c = X[(size_t)(J_F + j) * I_F + i];
        Tl[la][jj] = make_float4(a.x, a.y, c.x, c.y);
      }
    }
    __syncthreads();
#pragma unroll
    for (int p = 0; p < 4; ++p) {
      int ii = su + p * 8;
      int i = i0 + ii, j = j0 + la;
      if (i < I_F && j < J_F) {
        float4 x = Tl[ii][la];
        *(uint2*)(Xht + ((size_t)i * J_F + j) * 4) =
            make_uint2(f2h(x.x, x.y), f2h(x.z, x.w));
      }
    }
    return;
  }
  b -= NB_PACKT;
  if (b < NB_PACK) {
    if (!PK) return;
    const int i = (b % 9) * 256 + tid;
    if (i >= I_F) return;
    const int j0 = (b / 9) * 8;
    const int jend = min(8, J_F - j0);
    for (int jj = 0; jj < jend; ++jj) {
      const int j = j0 + jj;
      float2 a = X[(size_t)j * I_F + i];
      float2 c = X[(size_t)(J_F + j) * I_F + i];
      *(uint2*)(Xhj + ((size_t)j * I_F + i) * 4) =
          make_uint2(f2h(a.x, a.y), f2h(c.x, c.y));
    }
    return;
  }
  b -= NB_PACK;
  int t = b * 256 + tid;
  const int stride = NB_INIT * 256;
  for (int idx = t; idx < 2 * I_F * K_B; idx += stride) {
    int n = idx / (I_F * K_B);
    int r = idx % (I_F * K_B);
    int i = r / K_B, k = r % K_B;
    T[idx] = T0[(i * K_B + k) * M_CH + n];
  }
  for (int idx = t; idx < 2 * K_B * J_F; idx += stride) {
    int n = idx / (K_B * J_F);
    int r = idx % (K_B * J_F);
    int k = r / J_F, j = r % J_F;
    V[idx] = V0[(k * J_F + j) * M_CH + n];
  }
  for (int i = t; i < I_F; i += stride) {
    W[i * 8 + 0] = 1.f; W[i * 8 + 1] = 0.f; W[i * 8 + 2] = 0.f; W[i * 8 + 3] = 0.f;
    W[i * 8 + 4] = 0.f; W[i * 8 + 5] = 0.f; W[i * 8 + 6] = 1.f; W[i * 8 + 7] = 0.f;
  }
}

// ==== T update: block per i, threads stride j-pairs, reduce, in place ====
template<int PK>
__global__ __launch_bounds__(256) void k_T(const __half* __restrict__ Xht,
                                           const float2* __restrict__ X,
                                           const float* __restrict__ W,
                                           float* __restrict__ T,
                                           const float* __restrict__ V) {
  const int i = blockIdx.x;
  const int tid = threadIdx.x;
  float tr0[K_B], tr1[K_B];
#pragma unroll
  for (int k = 0; k < K_B; ++k) {
    tr0[k] = T[(size_t)i * 8 + k];
    tr1[k] = T[((size_t)I_F + i) * 8 + k];
  }
  const float4 w0 = ((const float4*)W)[i * 2];
  const float4 w1 = ((const float4*)W)[i * 2 + 1];
  float num0[K_B] = {}, den0[K_B] = {}, num1[K_B] = {}, den1[K_B] = {};
  if (PK) {
    const __half* xrow = Xht + (size_t)i * J_F * 4;
    for (int j2 = tid; j2 < J_F / 2; j2 += 256) {
      const int j = j2 * 2;
      uint4 raw = *(const uint4*)(xrow + (size_t)j * 4);
      float4 xa = h4f(raw.x, raw.y);
      float4 xb = h4f(raw.z, raw.w);
      float2 v0p[K_B], v1p[K_B];
      float R0a = 0.f, R0b = 0.f, R1a = 0.f, R1b = 0.f;
#pragma unroll
      for (int k = 0; k < K_B; ++k) {
        v0p[k] = *(const float2*)&V[(size_t)k * J_F + j];
        v1p[k] = *(const float2*)&V[(size_t)(K_B + k) * J_F + j];
        R0a += tr0[k] * v0p[k].x; R0b += tr0[k] * v0p[k].y;
        R1a += tr1[k] * v1p[k].x; R1b += tr1[k] * v1p[k].y;
      }
      float yr, yi;
      yr = w0.x * xa.x - w0.y * xa.y + w0.z * xa.z - w0.w * xa.w;
      yi = w0.x * xa.y + w0.y * xa.x + w0.z * xa.w + w0.w * xa.z;
      float p0a = yr * yr + yi * yi;
      yr = w1.x * xa.x - w1.y * xa.y + w1.z * xa.z - w1.w * xa.w;
      yi = w1.x * xa.y + w1.y * xa.x + w1.z * xa.w + w1.w * xa.z;
      float p1a = yr * yr + yi * yi;
      yr = w0.x * xb.x - w0.y * xb.y + w0.z * xb.z - w0.w * xb.w;
      yi = w0.x * xb.y + w0.y * xb.x + w0.z * xb.w + w0.w * xb.z;
      float p0b = yr * yr + yi * yi;
      yr = w1.x * xb.x - w1.y * xb.y + w1.z * xb.z - w1.w * xb.w;
      yi = w1.x * xb.y + w1.y * xb.x + w1.z * xb.w + w1.w * xb.z;
      float p1b = yr * yr + yi * yi;
      float a0a = p0a / (R0a * R0a), b0a = 1.f / R0a;
      float a1a = p1a / (R1a * R1a), b1a = 1.f / R1a;
      float a0b = p0b / (R0b * R0b), b0b = 1.f / R0b;
      float a1b = p1b / (R1b * R1b), b1b = 1.f / R1b;
#pragma unroll
      for (int k = 0; k < K_B; ++k) {
        num0[k] += a0a * v0p[k].x + a0b * v0p[k].y;
        den0[k] += b0a * v0p[k].x + b0b * v0p[k].y;
        num1[k] += a1a * v1p[k].x + a1b * v1p[k].y;
        den1[k] += b1a * v1p[k].x + b1b * v1p[k].y;
      }
    }
  } else {
    for (int j = tid; j < J_F; j += 256) {
      float2 a = X[(size_t)j * I_F + i];
      float2 c = X[(size_t)(J_F + j) * I_F + i];
      float4 x = make_float4(a.x, a.y, c.x, c.y);
      float yr = w0.x * x.x - w0.y * x.y + w0.z * x.z - w0.w * x.w;
      float yi = w0.x * x.y + w0.y * x.x + w0.z * x.w + w0.w * x.z;
      float p0 = yr * yr + yi * yi;
      float zr = w1.x * x.x - w1.y * x.y + w1.z * x.z - w1.w * x.w;
      float zi = w1.x * x.y + w1.y * x.x + w1.z * x.w + w1.w * x.z;
      float p1 = zr * zr + zi * zi;
      float v0[K_B], v1[K_B];
      float R0 = 0.f, R1 = 0.f;
#pragma unroll
      for (int k = 0; k < K_B; ++k) {
        v0[k] = V[(size_t)k * J_F + j];         R0 += tr0[k] * v0[k];
        v1[k] = V[(size_t)(K_B + k) * J_F + j]; R1 += tr1[k] * v1[k];
      }
      float a0 = p0 / (R0 * R0), b0 = 1.0f / R0;
      float a1 = p1 / (R1 * R1), b1 = 1.0f / R1;
#pragma unroll
      for (int k = 0; k < K_B; ++k) {
        num0[k] += a0 * v0[k]; den0[k] += b0 * v0[k];
        num1[k] += a1 * v1[k]; den1[k] += b1 * v1[k];
      }
    }
  }
  __shared__ float red[4][32];
  const int lane = tid & 63, wid = tid >> 6;
#pragma unroll
  for (int k = 0; k < K_B; ++k) {
    float a0 = num0[k], b0 = den0[k], a1 = num1[k], b1 = den1[k];
#pragma unroll
    for (int off = 32; off > 0; off >>= 1) {
      a0 += __shfl_xor(a0, off, 64);
      b0 += __shfl_xor(b0, off, 64);
      a1 += __shfl_xor(a1, off, 64);
      b1 += __shfl_xor(b1, off, 64);
    }
    if (lane == 0) {
      red[wid][k] = a0; red[wid][8 + k] = b0;
      red[wid][16 + k] = a1; red[wid][24 + k] = b1;
    }
  }
  __syncthreads();
  if (tid < 32) red[0][tid] = red[0][tid] + red[1][tid] + red[2][tid] + red[3][tid];
  __syncthreads();
  if (tid < 16) {
    int n = tid >> 3, k = tid & 7;
    float nu = red[0][n * 16 + k];
    float de = red[0][n * 16 + 8 + k];
    size_t idx = ((size_t)n * I_F + i) * 8 + k;
    float told = T[idx];
    T[idx] = fmaxf(told * sqrtf(nu / de), NMF_EPS);
  }
}

// ==== V update: block per j, threads stride i, reduce, in place ====
template<int PK>
__global__ __launch_bounds__(256) void k_V(const __half* __restrict__ Xhj,
                                           const float2* __restrict__ X,
                                           const float* __restrict__ W,
                                           const float* __restrict__ T,
                                           float* __restrict__ V) {
  const int j = blockIdx.x;
  const int tid = threadIdx.x;
  float vold0[K_B], vold1[K_B];
#pragma unroll
  for (int k = 0; k < K_B; ++k) {
    vold0[k] = V[(size_t)k * J_F + j];
    vold1[k] = V[(size_t)(K_B + k) * J_F + j];
  }
  float num0[K_B] = {}, den0[K_B] = {}, num1[K_B] = {}, den1[K_B] = {};
  const float* T1 = T + (size_t)I_F * K_B;
  const __half* xcol = Xhj + (size_t)j * I_F * 4;
  for (int i = tid; i < I_F; i += 256) {
    float4 x;
    if (PK) {
      uint2 raw = *(const uint2*)(xcol + (size_t)i * 4);
      x = h4f(raw.x, raw.y);
    } else {
      float2 a = X[(size_t)j * I_F + i];
      float2 c = X[(size_t)(J_F + j) * I_F + i];
      x = make_float4(a.x, a.y, c.x, c.y);
    }
    const float4 wa = ((const float4*)W)[i * 2];
    const float4 wb = ((const float4*)W)[i * 2 + 1];
    float yr = wa.x * x.x - wa.y * x.y + wa.z * x.z - wa.w * x.w;
    float yi = wa.x * x.y + wa.y * x.x + wa.z * x.w + wa.w * x.z;
    float p0 = yr * yr + yi * yi;
    float zr = wb.x * x.x - wb.y * x.y + wb.z * x.z - wb.w * x.w;
    float zi = wb.x * x.y + wb.y * x.x + wb.z * x.w + wb.w * x.z;
    float p1 = zr * zr + zi * zi;
    const float4 ta = *(const float4*)&T[i * 8];
    const float4 tb = *(const float4*)&T[i * 8 + 4];
    const float4 tc = *(const float4*)&T1[i * 8];
    const float4 td = *(const float4*)&T1[i * 8 + 4];
    float t0[K_B] = {ta.x, ta.y, ta.z, ta.w, tb.x, tb.y, tb.z, tb.w};
    float t1[K_B] = {tc.x, tc.y, tc.z, tc.w, td.x, td.y, td.z, td.w};
    float R0 = 0.f, R1 = 0.f;
#pragma unroll
    for (int k = 0; k < K_B; ++k) { R0 += t0[k] * vold0[k]; R1 += t1[k] * vold1[k]; }
    float a0 = p0 / (R0 * R0), b0 = 1.0f / R0;
    float a1 = p1 / (R1 * R1), b1 = 1.0f / R1;
#pragma unroll
    for (int k = 0; k < K_B; ++k) {
      num0[k] += a0 * t0[k]; den0[k] += b0 * t0[k];
      num1[k] += a1 * t1[k]; den1[k] += b1 * t1[k];
    }
  }
  __shared__ float red[4][32];
  const int lane = tid & 63, wid = tid >> 6;
#pragma unroll
  for (int k = 0; k < K_B; ++k) {
    float a0 = num0[k], b0 = den0[k], a1 = num1[k], b1 = den1[k];
#pragma unroll
    for (int off = 32; off > 0; off >>= 1) {
      a0 += __shfl_xor(a0, off, 64);
      b0 += __shfl_xor(b0, off, 64);
      a1 += __shfl_xor(a1, off, 64);
      b1 += __shfl_xor(b1, off, 64);
    }
    if (lane == 0) {
      red[wid][k] = a0; red[wid][8 + k] = b0;
      red[wid][16 + k] = a1; red[wid][24 + k] = b1;
    }
  }
  __syncthreads();
  if (tid < 32) red[0][tid] = red[0][tid] + red[1][tid] + red[2][tid] + red[3][tid];
  __syncthreads();
  if (tid < 16) {
    int n = tid >> 3, k = tid & 7;
    float nu = red[0][n * 16 + k];
    float de = red[0][n * 16 + 8 + k];
    size_t idx = ((size_t)n * K_B + k) * J_F + j;
    float vo = V[idx];
    V[idx] = fmaxf(vo * sqrtf(nu / de), NMF_EPS);
  }
}

// ==== D + solve: block per i, threads stride j-pairs, thread0 solves W ====
template<int PK>
__global__ __launch_bounds__(256) void k_D(const __half* __restrict__ Xht,
                                           const float2* __restrict__ X,
                                           const float* __restrict__ T,
                                           const float* __restrict__ V,
                                           float* __restrict__ W) {
  const int i = blockIdx.x;
  const int tid = threadIdx.x;
  float tr0[K_B], tr1[K_B];
#pragma unroll
  for (int k = 0; k < K_B; ++k) {
    tr0[k] = T[(size_t)i * K_B + k];
    tr1[k] = T[((size_t)I_F + i) * K_B + k];
  }
  float acc[8] = {};
  if (PK) {
    const __half* xrow = Xht + (size_t)i * J_F * 4;
    for (int j2 = tid; j2 < J_F / 2; j2 += 256) {
      const int j = j2 * 2;
      uint4 raw = *(const uint4*)(xrow + (size_t)j * 4);
      float4 xa = h4f(raw.x, raw.y);
      float4 xb = h4f(raw.z, raw.w);
      float R0a = 0.f, R0b = 0.f, R1a = 0.f, R1b = 0.f;
#pragma unroll
      for (int k = 0; k < K_B; ++k) {
        float2 v0p = *(const float2*)&V[(size_t)k * J_F + j];
        float2 v1p = *(const float2*)&V[(size_t)(K_B + k) * J_F + j];
        R0a += tr0[k] * v0p.x; R0b += tr0[k] * v0p.y;
        R1a += tr1[k] * v1p.x; R1b += tr1[k] * v1p.y;
      }
      float wv0a = 1.0f / (R0a + IP_EPS), wv0b = 1.0f / (R0b + IP_EPS);
      float wv1a = 1.0f / (R1a + IP_EPS), wv1b = 1.0f / (R1b + IP_EPS);
      float p00a = xa.x * xa.x + xa.y * xa.y, p00b = xb.x * xb.x + xb.y * xb.y;
      float p11a = xa.z * xa.z + xa.w * xa.w, p11b = xb.z * xb.z + xb.w * xb.w;
      float pra = xa.x * xa.z + xa.y * xa.w, prb = xb.x * xb.z + xb.y * xb.w;
      float pia = xa.y * xa.z - xa.x * xa.w, pib = xb.y * xb.z - xb.x * xb.w;
      acc[0] += wv0a * p00a + wv0b * p00b;
      acc[1] += wv0a * p11a + wv0b * p11b;
      acc[2] += wv0a * pra + wv0b * prb;
      acc[3] += wv0a * pia + wv0b * pib;
      acc[4] += wv1a * p00a + wv1b * p00b;
      acc[5] += wv1a * p11a + wv1b * p11b;
      acc[6] += wv1a * pra + wv1b * prb;
      acc[7] += wv1a * pia + wv1b * pib;
    }
  } else {
    for (int j = tid; j < J_F; j += 256) {
      float2 a = X[(size_t)j * I_F + i];
      float2 c = X[(size_t)(J_F + j) * I_F + i];
      float4 x = make_float4(a.x, a.y, c.x, c.y);
      float R0 = 0.f, R1 = 0.f;
#pragma unroll
      for (int k = 0; k < K_B; ++k) {
        R0 += tr0[k] * V[(size_t)k * J_F + j];
        R1 += tr1[k] * V[(size_t)(K_B + k) * J_F + j];
      }
      float wv0 = 1.0f / (R0 + IP_EPS);
      float wv1 = 1.0f / (R1 + IP_EPS);
      float p00 = x.x * x.x + x.y * x.y;
      float p11 = x.z * x.z + x.w * x.w;
      float pr = x.x * x.z + x.y * x.w;
      float pi = x.y * x.z - x.x * x.w;
      acc[0] += wv0 * p00; acc[1] += wv0 * p11; acc[2] += wv0 * pr; acc[3] += wv0 * pi;
      acc[4] += wv1 * p00; acc[5] += wv1 * p11; acc[6] += wv1 * pr; acc[7] += wv1 * pi;
    }
  }
  __shared__ float red[4][8];
  const int lane = tid & 63, wid = tid >> 6;
#pragma unroll
  for (int v = 0; v < 8; ++v) {
    float a = acc[v];
#pragma unroll
    for (int off = 32; off > 0; off >>= 1) a += __shfl_xor(a, off, 64);
    if (lane == 0) red[wid][v] = a;
  }
  __syncthreads();
  if (tid < 8) red[0][tid] = red[0][tid] + red[1][tid] + red[2][tid] + red[3][tid];
  __syncthreads();
  if (tid == 0) {
    float4 wa = ((const float4*)W)[i * 2];
    float4 wb = ((const float4*)W)[i * 2 + 1];
    float w00r = wa.x, w00i = wa.y, w01r = wa.z, w01i = wa.w;
    float w10r = wb.x, w10i = wb.y, w11r = wb.z, w11i = wb.w;
    const float invJ = 1.0f / (float)J_F;
#pragma unroll
    for (int n = 0; n < 2; ++n) {
      float d00 = red[0][n * 4 + 0] * invJ + IP_EPS;
      float d11 = red[0][n * 4 + 1] * invJ + IP_EPS;
      float d01r = red[0][n * 4 + 2] * invJ;
      float d01i = red[0][n * 4 + 3] * invJ;
      float A00r = w00r * d00 + (w01r * d01r + w01i * d01i);
      float A00i = w00i * d00 + (w01i * d01r - w01r * d01i);
      float A01r = (w00r * d01r - w00i * d01i) + w01r * d11;
      float A01i = (w00r * d01i + w00i * d01r) + w01i * d11;
      float A10r = w10r * d00 + (w11r * d01r + w11i * d01i);
      float A10i = w10i * d00 + (w11i * d01r - w11r * d01i);
      float A11r = (w10r * d01r - w10i * d01i) + w11r * d11;
      float A11i = (w10r * d01i + w10i * d01r) + w11i * d11;
      float detr = (A00r * A11r - A00i * A11i) - (A01r * A10r - A01i * A10i);
      float deti = (A00r * A11i + A00i * A11r) - (A01r * A10i + A01i * A10r);
      float idet = 1.0f / (detr * detr + deti * deti);
      float n0r, n0i, n1r, n1i;
      if (n == 0) { n0r = A11r; n0i = A11i; n1r = -A10r; n1i = -A10i; }
      else        { n0r = -A01r; n0i = -A01i; n1r = A00r; n1i = A00i; }
      float b0r = (n0r * detr + n0i * deti) * idet;
      float b0i = (n0i * detr - n0r * deti) * idet;
      float b1r = (n1r * detr + n1i * deti) * idet;
      float b1i = (n1i * detr - n1r * deti) * idet;
      float cr = d01r * b1r - d01i * b1i;
      float ci = d01r * b1i + d01i * b1r;
      float quad = d00 * (b0r * b0r + b0i * b0i) + d11 * (b1r * b1r + b1i * b1i)
                 + 2.0f * (b0r * cr + b0i * ci);
      float s = 1.0f / sqrtf(quad + IP_EPS);
      if (n == 0) { w00r = b0r * s; w00i = -b0i * s; w01r = b1r * s; w01i = -b1i * s; }
      else        { w10r = b0r * s; w10i = -b0i * s; w11r = b1r * s; w11i = -b1i * s; }
    }
    ((float4*)W)[i * 2]     = make_float4(w00r, w00i, w01r, w01i);
    ((float4*)W)[i * 2 + 1] = make_float4(w10r, w10i, w11r, w11i);
  }
}

// ---------------- final: original fp32 X for output precision ----------------
__global__ __launch_bounds__(256) void k_final(const float2* __restrict__ X,
                                               const float* __restrict__ W,
                                               float2* __restrict__ out) {
  const int i = blockIdx.x * 256 + threadIdx.x;
  if (i >= I_F) return;
  const float4 wa = ((const float4*)W)[i * 2];
  const float4 wb = ((const float4*)W)[i * 2 + 1];
  const int j0 = blockIdx.y * 8;
  const int jend = min(8, J_F - j0);
  for (int jj = 0; jj < jend; ++jj) {
    const int j = j0 + jj;
    float2 a = X[(size_t)j * I_F + i];
    float2 c = X[(size_t)(J_F + j) * I_F + i];
    float y0r = wa.x * a.x - wa.y * a.y + wa.z * c.x - wa.w * c.y;
    float y0i = wa.x * a.y + wa.y * a.x + wa.z * c.y + wa.w * c.x;
    out[(size_t)j * I_F + i] = make_float2(y0r, y0i);
    float y1r = wb.x * a.x - wb.y * a.y + wb.z * c.x - wb.w * c.y;
    float y1i = wb.x * a.y + wb.y * a.x + wb.z * c.y + wb.w * c.x;
    out[(size_t)(J_F + j) * I_F + i] = make_float2(y1r, y1i);
  }
}

extern "C" void kernel_launch(void* const* d_in, const int* in_sizes, int n_in,
                              void* d_out, int out_size, void* d_ws, size_t ws_size,
                              hipStream_t stream) {
  const float2* X = (const float2*)d_in[0];
  const float* T0 = (const float*)d_in[1];
  const float* V0 = (const float*)d_in[2];
  float2* outp = (float2*)d_out;
  char* ws = (char*)d_ws;
  size_t off = 0;
  auto alloc = [&](size_t bytes) -> void* {
    void* p = ws + off;
    off = (off + bytes + 255) & ~(size_t)255;
    return p;
  };
  float* W = (float*)alloc((size_t)I_F * 8 * 4);
  float* T = (float*)alloc((size_t)2 * I_F * K_B * 4);
  float* V = (float*)alloc((size_t)2 * K_B * J_F * 4);
  const size_t xh_sz = (size_t)J_F * I_F * 8;  // 32.8 MB each
  __half* Xht = nullptr;
  __half* Xhj = nullptr;
  if (off + 2 * xh_sz + 512 <= ws_size) {
    Xht = (__half*)alloc(xh_sz);
    Xhj = (__half*)alloc(xh_sz);
  }
  const int NBS = NB_PACKT + NB_PACK + NB_INIT;

  if (Xht) {
    k_setup<1><<<NBS, 256, 0, stream>>>(X, T0, V0, T, V, W, Xht, Xhj);
    for (int it = 0; it < N_IT; ++it) {
      k_T<1><<<I_F, 256, 0, stream>>>(Xht, X, W, T, V);
      k_V<1><<<J_F, 256, 0, stream>>>(Xhj, X, W, T, V);
      k_D<1><<<I_F, 256, 0, stream>>>(Xht, X, T, V, W);
    }
  } else {
    k_setup<0><<<NBS, 256, 0, stream>>>(X, T0, V0, T, V, W, nullptr, nullptr);
    for (int it = 0; it < N_IT; ++it) {
      k_T<0><<<I_F, 256, 0, stream>>>(nullptr, X, W, T, V);
      k_V<0><<<J_F, 256, 0, stream>>>(nullptr, X, W, T, V);
      k_D<0><<<I_F, 256, 0, stream>>>(nullptr, X, T, V, W);
    }
  }
  k_final<<<dim3(9, 250), 256, 0, stream>>>(X, W, outp);
}

// Round 16
// 466.967 us; speedup vs baseline: 4.9730x; 1.0019x over previous
//
#include <hip/hip_runtime.h>
#include <hip/hip_fp16.h>

#define M_CH 2
#define J_F 2000
#define I_F 2049
#define K_B 8
#define N_IT 5
#define NMF_EPS 1e-20f
#define IP_EPS 1e-20f

#define NB_TILE (65 * 63)
#define NB_INIT 128

__device__ __forceinline__ float2 h2f(unsigned u) {
  __half2 h = *reinterpret_cast<__half2*>(&u);
  return __half22float2(h);
}
__device__ __forceinline__ float4 h4f(unsigned lo, unsigned hi) {
  float2 a = h2f(lo), b = h2f(hi);
  return make_float4(a.x, a.y, b.x, b.y);
}
__device__ __forceinline__ unsigned f2h(float a, float b) {
  __half2 h = __floats2half2_rn(a, b);
  return *reinterpret_cast<unsigned*>(&h);
}

// ===== single-pass setup: read X once -> Xhj + Xht(fp16) ; init T,V,W =====
template<int PK>
__global__ __launch_bounds__(256) void k_setup(const float2* __restrict__ X,
                                               const float* __restrict__ T0,
                                               const float* __restrict__ V0,
                                               float* __restrict__ T,
                                               float* __restrict__ V,
                                               float* __restrict__ W,
                                               __half* __restrict__ Xht,
                                               __half* __restrict__ Xhj) {
  int b = blockIdx.x;
  const int tid = threadIdx.x;
  if (b < NB_TILE) {
    if (!PK) return;
    __shared__ float4 Tl[32][33];
    const int i0 = (b % 65) * 32, j0 = (b / 65) * 32;
    const int la = tid & 31, su = tid >> 5;
#pragma unroll
    for (int p = 0; p < 4; ++p) {
      int jj = su + p * 8;
      int i = i0 + la, j = j0 + jj;
      if (i < I_F && j < J_F) {
        float2 a = X[(size_t)j * I_F + i];
        float2 c = X[(size_t)(J_F + j) * I_F + i];
        float4 x = make_float4(a.x, a.y, c.x, c.y);
        Tl[la][jj] = x;
        *(uint2*)(Xhj + ((size_t)j * I_F + i) * 4) =
            make_uint2(f2h(x.x, x.y), f2h(x.z, x.w));
      }
    }
    __syncthreads();
#pragma unroll
    for (int p = 0; p < 4; ++p) {
      int ii = su + p * 8;
      int i = i0 + ii, j = j0 + la;
      if (i < I_F && j < J_F) {
        float4 x = Tl[ii][la];
        *(uint2*)(Xht + ((size_t)i * J_F + j) * 4) =
            make_uint2(f2h(x.x, x.y), f2h(x.z, x.w));
      }
    }
    return;
  }
  b -= NB_TILE;
  int t = b * 256 + tid;
  const int stride = NB_INIT * 256;
  for (int idx = t; idx < 2 * I_F * K_B; idx += stride) {
    int n = idx / (I_F * K_B);
    int r = idx % (I_F * K_B);
    int i = r / K_B, k = r % K_B;
    T[idx] = T0[(i * K_B + k) * M_CH + n];
  }
  for (int idx = t; idx < 2 * K_B * J_F; idx += stride) {
    int n = idx / (K_B * J_F);
    int r = idx % (K_B * J_F);
    int k = r / J_F, j = r % J_F;
    V[idx] = V0[(k * J_F + j) * M_CH + n];
  }
  for (int i = t; i < I_F; i += stride) {
    W[i * 8 + 0] = 1.f; W[i * 8 + 1] = 0.f; W[i * 8 + 2] = 0.f; W[i * 8 + 3] = 0.f;
    W[i * 8 + 4] = 0.f; W[i * 8 + 5] = 0.f; W[i * 8 + 6] = 1.f; W[i * 8 + 7] = 0.f;
  }
}

// ==== T phase body: row i, threads stride j-pairs, reduce, update T ====
template<int PK>
__device__ __forceinline__ void t_phase(const int i, const __half* __restrict__ Xht,
                                        const float2* __restrict__ X,
                                        const float4 w0, const float4 w1,
                                        float* __restrict__ T, const float* __restrict__ V,
                                        float (*red)[32]) {
  const int tid = threadIdx.x;
  float tr0[K_B], tr1[K_B];
#pragma unroll
  for (int k = 0; k < K_B; ++k) {
    tr0[k] = T[(size_t)i * 8 + k];
    tr1[k] = T[((size_t)I_F + i) * 8 + k];
  }
  float num0[K_B] = {}, den0[K_B] = {}, num1[K_B] = {}, den1[K_B] = {};
  if (PK) {
    const __half* xrow = Xht + (size_t)i * J_F * 4;
    for (int j2 = tid; j2 < J_F / 2; j2 += 256) {
      const int j = j2 * 2;
      uint4 raw = *(const uint4*)(xrow + (size_t)j * 4);
      float4 xa = h4f(raw.x, raw.y);
      float4 xb = h4f(raw.z, raw.w);
      float2 v0p[K_B], v1p[K_B];
      float R0a = 0.f, R0b = 0.f, R1a = 0.f, R1b = 0.f;
#pragma unroll
      for (int k = 0; k < K_B; ++k) {
        v0p[k] = *(const float2*)&V[(size_t)k * J_F + j];
        v1p[k] = *(const float2*)&V[(size_t)(K_B + k) * J_F + j];
        R0a += tr0[k] * v0p[k].x; R0b += tr0[k] * v0p[k].y;
        R1a += tr1[k] * v1p[k].x; R1b += tr1[k] * v1p[k].y;
      }
      float yr, yi;
      yr = w0.x * xa.x - w0.y * xa.y + w0.z * xa.z - w0.w * xa.w;
      yi = w0.x * xa.y + w0.y * xa.x + w0.z * xa.w + w0.w * xa.z;
      float p0a = yr * yr + yi * yi;
      yr = w1.x * xa.x - w1.y * xa.y + w1.z * xa.z - w1.w * xa.w;
      yi = w1.x * xa.y + w1.y * xa.x + w1.z * xa.w + w1.w * xa.z;
      float p1a = yr * yr + yi * yi;
      yr = w0.x * xb.x - w0.y * xb.y + w0.z * xb.z - w0.w * xb.w;
      yi = w0.x * xb.y + w0.y * xb.x + w0.z * xb.w + w0.w * xb.z;
      float p0b = yr * yr + yi * yi;
      yr = w1.x * xb.x - w1.y * xb.y + w1.z * xb.z - w1.w * xb.w;
      yi = w1.x * xb.y + w1.y * xb.x + w1.z * xb.w + w1.w * xb.z;
      float p1b = yr * yr + yi * yi;
      float a0a = p0a / (R0a * R0a), b0a = 1.f / R0a;
      float a1a = p1a / (R1a * R1a), b1a = 1.f / R1a;
      float a0b = p0b / (R0b * R0b), b0b = 1.f / R0b;
      float a1b = p1b / (R1b * R1b), b1b = 1.f / R1b;
#pragma unroll
      for (int k = 0; k < K_B; ++k) {
        num0[k] += a0a * v0p[k].x + a0b * v0p[k].y;
        den0[k] += b0a * v0p[k].x + b0b * v0p[k].y;
        num1[k] += a1a * v1p[k].x + a1b * v1p[k].y;
        den1[k] += b1a * v1p[k].x + b1b * v1p[k].y;
      }
    }
  } else {
    for (int j = tid; j < J_F; j += 256) {
      float2 a = X[(size_t)j * I_F + i];
      float2 c = X[(size_t)(J_F + j) * I_F + i];
      float4 x = make_float4(a.x, a.y, c.x, c.y);
      float yr = w0.x * x.x - w0.y * x.y + w0.z * x.z - w0.w * x.w;
      float yi = w0.x * x.y + w0.y * x.x + w0.z * x.w + w0.w * x.z;
      float p0 = yr * yr + yi * yi;
      float zr = w1.x * x.x - w1.y * x.y + w1.z * x.z - w1.w * x.w;
      float zi = w1.x * x.y + w1.y * x.x + w1.z * x.w + w1.w * x.z;
      float p1 = zr * zr + zi * zi;
      float v0[K_B], v1[K_B];
      float R0 = 0.f, R1 = 0.f;
#pragma unroll
      for (int k = 0; k < K_B; ++k) {
        v0[k] = V[(size_t)k * J_F + j];         R0 += tr0[k] * v0[k];
        v1[k] = V[(size_t)(K_B + k) * J_F + j]; R1 += tr1[k] * v1[k];
      }
      float a0 = p0 / (R0 * R0), b0 = 1.0f / R0;
      float a1 = p1 / (R1 * R1), b1 = 1.0f / R1;
#pragma unroll
      for (int k = 0; k < K_B; ++k) {
        num0[k] += a0 * v0[k]; den0[k] += b0 * v0[k];
        num1[k] += a1 * v1[k]; den1[k] += b1 * v1[k];
      }
    }
  }
  const int lane = tid & 63, wid = tid >> 6;
#pragma unroll
  for (int k = 0; k < K_B; ++k) {
    float a0 = num0[k], b0 = den0[k], a1 = num1[k], b1 = den1[k];
#pragma unroll
    for (int off = 32; off > 0; off >>= 1) {
      a0 += __shfl_xor(a0, off, 64);
      b0 += __shfl_xor(b0, off, 64);
      a1 += __shfl_xor(a1, off, 64);
      b1 += __shfl_xor(b1, off, 64);
    }
    if (lane == 0) {
      red[wid][k] = a0; red[wid][8 + k] = b0;
      red[wid][16 + k] = a1; red[wid][24 + k] = b1;
    }
  }
  __syncthreads();
  if (tid < 32) red[0][tid] = red[0][tid] + red[1][tid] + red[2][tid] + red[3][tid];
  __syncthreads();
  if (tid < 16) {
    int n = tid >> 3, k = tid & 7;
    float nu = red[0][n * 16 + k];
    float de = red[0][n * 16 + 8 + k];
    size_t idx = ((size_t)n * I_F + i) * 8 + k;
    float told = T[idx];
    T[idx] = fmaxf(told * sqrtf(nu / de), NMF_EPS);
  }
}

// ==== D phase body: row i, reduce 8 sums, thread0 solves, W row -> wrow ====
template<int PK>
__device__ __forceinline__ void d_phase(const int i, const __half* __restrict__ Xht,
                                        const float2* __restrict__ X,
                                        const float* __restrict__ T,
                                        const float* __restrict__ V,
                                        float* __restrict__ W,
                                        float (*red)[32], float* wrow) {
  const int tid = threadIdx.x;
  float tr0[K_B], tr1[K_B];
#pragma unroll
  for (int k = 0; k < K_B; ++k) {
    tr0[k] = T[(size_t)i * K_B + k];
    tr1[k] = T[((size_t)I_F + i) * K_B + k];
  }
  float acc[8] = {};
  if (PK) {
    const __half* xrow = Xht + (size_t)i * J_F * 4;
    for (int j2 = tid; j2 < J_F / 2; j2 += 256) {
      const int j = j2 * 2;
      uint4 raw = *(const uint4*)(xrow + (size_t)j * 4);
      float4 xa = h4f(raw.x, raw.y);
      float4 xb = h4f(raw.z, raw.w);
      float R0a = 0.f, R0b = 0.f, R1a = 0.f, R1b = 0.f;
#pragma unroll
      for (int k = 0; k < K_B; ++k) {
        float2 v0p = *(const float2*)&V[(size_t)k * J_F + j];
        float2 v1p = *(const float2*)&V[(size_t)(K_B + k) * J_F + j];
        R0a += tr0[k] * v0p.x; R0b += tr0[k] * v0p.y;
        R1a += tr1[k] * v1p.x; R1b += tr1[k] * v1p.y;
      }
      float wv0a = 1.0f / (R0a + IP_EPS), wv0b = 1.0f / (R0b + IP_EPS);
      float wv1a = 1.0f / (R1a + IP_EPS), wv1b = 1.0f / (R1b + IP_EPS);
      float p00a = xa.x * xa.x + xa.y * xa.y, p00b = xb.x * xb.x + xb.y * xb.y;
      float p11a = xa.z * xa.z + xa.w * xa.w, p11b = xb.z * xb.z + xb.w * xb.w;
      float pra = xa.x * xa.z + xa.y * xa.w, prb = xb.x * xb.z + xb.y * xb.w;
      float pia = xa.y * xa.z - xa.x * xa.w, pib = xb.y * xb.z - xb.x * xb.w;
      acc[0] += wv0a * p00a + wv0b * p00b;
      acc[1] += wv0a * p11a + wv0b * p11b;
      acc[2] += wv0a * pra + wv0b * prb;
      acc[3] += wv0a * pia + wv0b * pib;
      acc[4] += wv1a * p00a + wv1b * p00b;
      acc[5] += wv1a * p11a + wv1b * p11b;
      acc[6] += wv1a * pra + wv1b * prb;
      acc[7] += wv1a * pia + wv1b * pib;
    }
  } else {
    for (int j = tid; j < J_F; j += 256) {
      float2 a = X[(size_t)j * I_F + i];
      float2 c = X[(size_t)(J_F + j) * I_F + i];
      float4 x = make_float4(a.x, a.y, c.x, c.y);
      float R0 = 0.f, R1 = 0.f;
#pragma unroll
      for (int k = 0; k < K_B; ++k) {
        R0 += tr0[k] * V[(size_t)k * J_F + j];
        R1 += tr1[k] * V[(size_t)(K_B + k) * J_F + j];
      }
      float wv0 = 1.0f / (R0 + IP_EPS);
      float wv1 = 1.0f / (R1 + IP_EPS);
      float p00 = x.x * x.x + x.y * x.y;
      float p11 = x.z * x.z + x.w * x.w;
      float pr = x.x * x.z + x.y * x.w;
      float pi = x.y * x.z - x.x * x.w;
      acc[0] += wv0 * p00; acc[1] += wv0 * p11; acc[2] += wv0 * pr; acc[3] += wv0 * pi;
      acc[4] += wv1 * p00; acc[5] += wv1 * p11; acc[6] += wv1 * pr; acc[7] += wv1 * pi;
    }
  }
  const int lane = tid & 63, wid = tid >> 6;
#pragma unroll
  for (int v = 0; v < 8; ++v) {
    float a = acc[v];
#pragma unroll
    for (int off = 32; off > 0; off >>= 1) a += __shfl_xor(a, off, 64);
    if (lane == 0) red[wid][v] = a;
  }
  __syncthreads();
  if (tid < 8) red[0][tid] = red[0][tid] + red[1][tid] + red[2][tid] + red[3][tid];
  __syncthreads();
  if (tid == 0) {
    float4 wa = ((const float4*)W)[i * 2];
    float4 wb = ((const float4*)W)[i * 2 + 1];
    float w00r = wa.x, w00i = wa.y, w01r = wa.z, w01i = wa.w;
    float w10r = wb.x, w10i = wb.y, w11r = wb.z, w11i = wb.w;
    const float invJ = 1.0f / (float)J_F;
#pragma unroll
    for (int n = 0; n < 2; ++n) {
      float d00 = red[0][n * 4 + 0] * invJ + IP_EPS;
      float d11 = red[0][n * 4 + 1] * invJ + IP_EPS;
      float d01r = red[0][n * 4 + 2] * invJ;
      float d01i = red[0][n * 4 + 3] * invJ;
      float A00r = w00r * d00 + (w01r * d01r + w01i * d01i);
      float A00i = w00i * d00 + (w01i * d01r - w01r * d01i);
      float A01r = (w00r * d01r - w00i * d01i) + w01r * d11;
      float A01i = (w00r * d01i + w00i * d01r) + w01i * d11;
      float A10r = w10r * d00 + (w11r * d01r + w11i * d01i);
      float A10i = w10i * d00 + (w11i * d01r - w11r * d01i);
      float A11r = (w10r * d01r - w10i * d01i) + w11r * d11;
      float A11i = (w10r * d01i + w10i * d01r) + w11i * d11;
      float detr = (A00r * A11r - A00i * A11i) - (A01r * A10r - A01i * A10i);
      float deti = (A00r * A11i + A00i * A11r) - (A01r * A10i + A01i * A10r);
      float idet = 1.0f / (detr * detr + deti * deti);
      float n0r, n0i, n1r, n1i;
      if (n == 0) { n0r = A11r; n0i = A11i; n1r = -A10r; n1i = -A10i; }
      else        { n0r = -A01r; n0i = -A01i; n1r = A00r; n1i = A00i; }
      float b0r = (n0r * detr + n0i * deti) * idet;
      float b0i = (n0i * detr - n0r * deti) * idet;
      float b1r = (n1r * detr + n1i * deti) * idet;
      float b1i = (n1i * detr - n1r * deti) * idet;
      float cr = d01r * b1r - d01i * b1i;
      float ci = d01r * b1i + d01i * b1r;
      float quad = d00 * (b0r * b0r + b0i * b0i) + d11 * (b1r * b1r + b1i * b1i)
                 + 2.0f * (b0r * cr + b0i * ci);
      float s = 1.0f / sqrtf(quad + IP_EPS);
      if (n == 0) { w00r = b0r * s; w00i = -b0i * s; w01r = b1r * s; w01i = -b1i * s; }
      else        { w10r = b0r * s; w10i = -b0i * s; w11r = b1r * s; w11i = -b1i * s; }
    }
    ((float4*)W)[i * 2]     = make_float4(w00r, w00i, w01r, w01i);
    ((float4*)W)[i * 2 + 1] = make_float4(w10r, w10i, w11r, w11i);
    wrow[0] = w00r; wrow[1] = w00i; wrow[2] = w01r; wrow[3] = w01i;
    wrow[4] = w10r; wrow[5] = w10i; wrow[6] = w11r; wrow[7] = w11i;
  }
  __syncthreads();
}

// ---- standalone kernels ----
template<int PK>
__global__ __launch_bounds__(256) void k_T(const __half* __restrict__ Xht,
                                           const float2* __restrict__ X,
                                           const float* __restrict__ W,
                                           float* __restrict__ T,
                                           const float* __restrict__ V) {
  __shared__ float red[4][32];
  const int i = blockIdx.x;
  const float4 w0 = ((const float4*)W)[i * 2];
  const float4 w1 = ((const float4*)W)[i * 2 + 1];
  t_phase<PK>(i, Xht, X, w0, w1, T, V, red);
}

template<int PK>
__global__ __launch_bounds__(256) void k_D(const __half* __restrict__ Xht,
                                           const float2* __restrict__ X,
                                           const float* __restrict__ T,
                                           const float* __restrict__ V,
                                           float* __restrict__ W) {
  __shared__ float red[4][32];
  __shared__ float wrow[8];
  d_phase<PK>(blockIdx.x, Xht, X, T, V, W, red, wrow);
}

// D of iter it fused with T of iter it+1 (same row; new W row via LDS)
template<int PK>
__global__ __launch_bounds__(256) void k_DT(const __half* __restrict__ Xht,
                                            const float2* __restrict__ X,
                                            float* __restrict__ T,
                                            const float* __restrict__ V,
                                            float* __restrict__ W) {
  __shared__ float red[4][32];
  __shared__ float wrow[8];
  const int i = blockIdx.x;
  d_phase<PK>(i, Xht, X, T, V, W, red, wrow);
  const float4 w0 = make_float4(wrow[0], wrow[1], wrow[2], wrow[3]);
  const float4 w1 = make_float4(wrow[4], wrow[5], wrow[6], wrow[7]);
  __syncthreads();
  t_phase<PK>(i, Xht, X, w0, w1, T, V, red);
}

// ==== V update: block per j, threads stride i, reduce, in place ====
template<int PK>
__global__ __launch_bounds__(256) void k_V(const __half* __restrict__ Xhj,
                                           const float2* __restrict__ X,
                                           const float* __restrict__ W,
                                           const float* __restrict__ T,
                                           float* __restrict__ V) {
  const int j = blockIdx.x;
  const int tid = threadIdx.x;
  float vold0[K_B], vold1[K_B];
#pragma unroll
  for (int k = 0; k < K_B; ++k) {
    vold0[k] = V[(size_t)k * J_F + j];
    vold1[k] = V[(size_t)(K_B + k) * J_F + j];
  }
  float num0[K_B] = {}, den0[K_B] = {}, num1[K_B] = {}, den1[K_B] = {};
  const float* T1 = T + (size_t)I_F * K_B;
  const __half* xcol = Xhj + (size_t)j * I_F * 4;
  for (int i = tid; i < I_F; i += 256) {
    float4 x;
    if (PK) {
      uint2 raw = *(const uint2*)(xcol + (size_t)i * 4);
      x = h4f(raw.x, raw.y);
    } else {
      float2 a = X[(size_t)j * I_F + i];
      float2 c = X[(size_t)(J_F + j) * I_F + i];
      x = make_float4(a.x, a.y, c.x, c.y);
    }
    const float4 wa = ((const float4*)W)[i * 2];
    const float4 wb = ((const float4*)W)[i * 2 + 1];
    float yr = wa.x * x.x - wa.y * x.y + wa.z * x.z - wa.w * x.w;
    float yi = wa.x * x.y + wa.y * x.x + wa.z * x.w + wa.w * x.z;
    float p0 = yr * yr + yi * yi;
    float zr = wb.x * x.x - wb.y * x.y + wb.z * x.z - wb.w * x.w;
    float zi = wb.x * x.y + wb.y * x.x + wb.z * x.w + wb.w * x.z;
    float p1 = zr * zr + zi * zi;
    const float4 ta = *(const float4*)&T[i * 8];
    const float4 tb = *(const float4*)&T[i * 8 + 4];
    const float4 tc = *(const float4*)&T1[i * 8];
    const float4 td = *(const float4*)&T1[i * 8 + 4];
    float t0[K_B] = {ta.x, ta.y, ta.z, ta.w, tb.x, tb.y, tb.z, tb.w};
    float t1[K_B] = {tc.x, tc.y, tc.z, tc.w, td.x, td.y, td.z, td.w};
    float R0 = 0.f, R1 = 0.f;
#pragma unroll
    for (int k = 0; k < K_B; ++k) { R0 += t0[k] * vold0[k]; R1 += t1[k] * vold1[k]; }
    float a0 = p0 / (R0 * R0), b0 = 1.0f / R0;
    float a1 = p1 / (R1 * R1), b1 = 1.0f / R1;
#pragma unroll
    for (int k = 0; k < K_B; ++k) {
      num0[k] += a0 * t0[k]; den0[k] += b0 * t0[k];
      num1[k] += a1 * t1[k]; den1[k] += b1 * t1[k];
    }
  }
  __shared__ float red[4][32];
  const int lane = tid & 63, wid = tid >> 6;
#pragma unroll
  for (int k = 0; k < K_B; ++k) {
    float a0 = num0[k], b0 = den0[k], a1 = num1[k], b1 = den1[k];
#pragma unroll
    for (int off = 32; off > 0; off >>= 1) {
      a0 += __shfl_xor(a0, off, 64);
      b0 += __shfl_xor(b0, off, 64);
      a1 += __shfl_xor(a1, off, 64);
      b1 += __shfl_xor(b1, off, 64);
    }
    if (lane == 0) {
      red[wid][k] = a0; red[wid][8 + k] = b0;
      red[wid][16 + k] = a1; red[wid][24 + k] = b1;
    }
  }
  __syncthreads();
  if (tid < 32) red[0][tid] = red[0][tid] + red[1][tid] + red[2][tid] + red[3][tid];
  __syncthreads();
  if (tid < 16) {
    int n = tid >> 3, k = tid & 7;
    float nu = red[0][n * 16 + k];
    float de = red[0][n * 16 + 8 + k];
    size_t idx = ((size_t)n * K_B + k) * J_F + j;
    float vo = V[idx];
    V[idx] = fmaxf(vo * sqrtf(nu / de), NMF_EPS);
  }
}

// ---------------- final: fp16 Xhj (precision: ~2e-3 abs, thr 0.1075) ----------------
template<int PK>
__global__ __launch_bounds__(256) void k_final(const __half* __restrict__ Xhj,
                                               const float2* __restrict__ X,
                                               const float* __restrict__ W,
                                               float2* __restrict__ out) {
  const int i = blockIdx.x * 256 + threadIdx.x;
  if (i >= I_F) return;
  const float4 wa = ((const float4*)W)[i * 2];
  const float4 wb = ((const float4*)W)[i * 2 + 1];
  const int j0 = blockIdx.y * 8;
  const int jend = min(8, J_F - j0);
  for (int jj = 0; jj < jend; ++jj) {
    const int j = j0 + jj;
    float4 x;
    if (PK) {
      uint2 raw = *(const uint2*)(Xhj + ((size_t)j * I_F + i) * 4);
      x = h4f(raw.x, raw.y);
    } else {
      float2 a = X[(size_t)j * I_F + i];
      float2 c = X[(size_t)(J_F + j) * I_F + i];
      x = make_float4(a.x, a.y, c.x, c.y);
    }
    float y0r = wa.x * x.x - wa.y * x.y + wa.z * x.z - wa.w * x.w;
    float y0i = wa.x * x.y + wa.y * x.x + wa.z * x.w + wa.w * x.z;
    out[(size_t)j * I_F + i] = make_float2(y0r, y0i);
    float y1r = wb.x * x.x - wb.y * x.y + wb.z * x.z - wb.w * x.w;
    float y1i = wb.x * x.y + wb.y * x.x + wb.z * x.w + wb.w * x.z;
    out[(size_t)(J_F + j) * I_F + i] = make_float2(y1r, y1i);
  }
}

extern "C" void kernel_launch(void* const* d_in, const int* in_sizes, int n_in,
                              void* d_out, int out_size, void* d_ws, size_t ws_size,
                              hipStream_t stream) {
  const float2* X = (const float2*)d_in[0];
  const float* T0 = (const float*)d_in[1];
  const float* V0 = (const float*)d_in[2];
  float2* outp = (float2*)d_out;
  char* ws = (char*)d_ws;
  size_t off = 0;
  auto alloc = [&](size_t bytes) -> void* {
    void* p = ws + off;
    off = (off + bytes + 255) & ~(size_t)255;
    return p;
  };
  float* W = (float*)alloc((size_t)I_F * 8 * 4);
  float* T = (float*)alloc((size_t)2 * I_F * K_B * 4);
  float* V = (float*)alloc((size_t)2 * K_B * J_F * 4);
  const size_t xh_sz = (size_t)J_F * I_F * 8;  // 32.8 MB each
  __half* Xht = nullptr;
  __half* Xhj = nullptr;
  if (off + 2 * xh_sz + 512 <= ws_size) {
    Xht = (__half*)alloc(xh_sz);
    Xhj = (__half*)alloc(xh_sz);
  }
  const int NBS = NB_TILE + NB_INIT;

  if (Xht) {
    k_setup<1><<<NBS, 256, 0, stream>>>(X, T0, V0, T, V, W, Xht, Xhj);
    k_T<1><<<I_F, 256, 0, stream>>>(Xht, X, W, T, V);
    for (int it = 0; it < N_IT; ++it) {
      k_V<1><<<J_F, 256, 0, stream>>>(Xhj, X, W, T, V);
      if (it < N_IT - 1)
        k_DT<1><<<I_F, 256, 0, stream>>>(Xht, X, T, V, W);
      else
        k_D<1><<<I_F, 256, 0, stream>>>(Xht, X, T, V, W);
    }
    k_final<1><<<dim3(9, 250), 256, 0, stream>>>(Xhj, X, W, outp);
  } else {
    k_setup<0><<<NBS, 256, 0, stream>>>(X, T0, V0, T, V, W, nullptr, nullptr);
    k_T<0><<<I_F, 256, 0, stream>>>(nullptr, X, W, T, V);
    for (int it = 0; it < N_IT; ++it) {
      k_V<0><<<J_F, 256, 0, stream>>>(nullptr, X, W, T, V);
      if (it < N_IT - 1)
        k_DT<0><<<I_F, 256, 0, stream>>>(nullptr, X, T, V, W);
      else
        k_D<0><<<I_F, 256, 0, stream>>>(nullptr, X, T, V, W);
    }
    k_final<0><<<dim3(9, 250), 256, 0, stream>>>(nullptr, X, W, outp);
  }
}